// Round 2
// baseline (264.258 us; speedup 1.0000x reference)
//
#include <hip/hip_runtime.h>
#include <hip/hip_bf16.h>

#define N_NODES 50000
#define N_EDGES 800000
#define IN_F 256
#define HEADS 8
#define OUT_F 32
#define HF (HEADS * OUT_F)   // 256
#define SLOPE 0.2f

typedef __attribute__((ext_vector_type(8))) short bf16x8;
typedef __attribute__((ext_vector_type(4))) float f32x4;

__device__ __forceinline__ ushort f2bf(float f) {
  union { float f; unsigned u; } x;
  x.f = f;
  unsigned r = x.u + 0x7FFFu + ((x.u >> 16) & 1u);  // RNE
  return (ushort)(r >> 16);
}

__device__ __forceinline__ float bf2f_lo(unsigned u) {
  return __uint_as_float(u << 16);
}
__device__ __forceinline__ float bf2f_hi(unsigned u) {
  return __uint_as_float(u & 0xFFFF0000u);
}

// ---------------------------------------------------------------------------
// Kernel P: fused prep. blocks 0..63: Bt transpose+convert; block 64: wl;
// blocks 65..: CSR row_ptr binary search. All three are independent.
// ---------------------------------------------------------------------------
#define ROWPTR_BLOCKS ((N_NODES + 1 + 255) / 256)

__global__ __launch_bounds__(256) void prep_kernel(
    const float* __restrict__ fc_w, const float* __restrict__ attn_l,
    ushort* __restrict__ Bt, float* __restrict__ wl,
    const int* __restrict__ dst, int* __restrict__ row_ptr) {
  __shared__ float tile[32][33];
  const int b = blockIdx.x;
  const int t = threadIdx.x;

  if (b < 64) {
    // --- Bt[n][k] = bf16(fc_w[k][n]), 32x32 tile
    const int bx = (b & 7) * 32;   // n block
    const int by = (b >> 3) * 32;  // k block
    const int tx = t & 31;
    const int ty = t >> 5;  // 0..7
#pragma unroll
    for (int i = 0; i < 32; i += 8)
      tile[ty + i][tx] = fc_w[(size_t)(by + ty + i) * HF + bx + tx];
    __syncthreads();
#pragma unroll
    for (int i = 0; i < 32; i += 8)
      Bt[(size_t)(bx + ty + i) * IN_F + by + tx] = f2bf(tile[tx][ty + i]);
  } else if (b == 64) {
    // --- wl[k,h] = sum_f fc_w[k, h*32+f] * attn_l[h,f]
#pragma unroll
    for (int ii = 0; ii < 8; ++ii) {
      const int idx = ii * 256 + t;  // 0..2047
      const int k = idx >> 3;
      const int h = idx & 7;
      const float* fp = &fc_w[(size_t)k * HF + h * OUT_F];
      const float* ap = &attn_l[h * OUT_F];
      float acc = 0.f;
#pragma unroll
      for (int f = 0; f < OUT_F; f += 4) {
        float4 a = *(const float4*)&fp[f];
        float4 bb = *(const float4*)&ap[f];
        acc += a.x * bb.x + a.y * bb.y + a.z * bb.z + a.w * bb.w;
      }
      wl[idx] = acc;
    }
  } else {
    // --- row_ptr
    const int i = (b - 65) * 256 + t;
    if (i <= N_NODES) {
      int lo = 0, hi = N_EDGES;
      while (lo < hi) {
        int mid = (lo + hi) >> 1;
        if (dst[mid] < i) lo = mid + 1; else hi = mid;
      }
      row_ptr[i] = lo;
    }
  }
}

// ---------------------------------------------------------------------------
// Kernel 1: bf16 MFMA GEMM  Cb[M,256](bf16) = A[M,256](f32) @ B[256,256]
// BM=64 x BN=256 tile, BK=32, 256 threads = 4 waves. Wave w owns cols w*64.
// ---------------------------------------------------------------------------
#define BM 64
#define BN 256
#define BK 32
#define LDA 40   // padded LDS row stride (bf16 elems): 80 B, 16B-aligned

__global__ __launch_bounds__(256) void gemm_mfma(
    const float* __restrict__ A, const ushort* __restrict__ Bt,
    ushort* __restrict__ Cb, int M) {
  __shared__ __align__(16) ushort As[BM * LDA];   // [m][k]  5 KB
  __shared__ __align__(16) ushort Bs[BN * LDA];   // [n][k] 20 KB

  const int t = threadIdx.x;
  const int wave = t >> 6;
  const int lane = t & 63;
  const int m0 = blockIdx.x * BM;

  const int ar = t >> 2;
  const int ak = (t & 3) * 8;
  const int br = t >> 2;
  const int bk = (t & 3) * 8;

  const int q = lane >> 4;
  const int l16 = lane & 15;
  const int wn = wave * 64;

  f32x4 acc[4][4] = {};

  for (int k0 = 0; k0 < IN_F; k0 += BK) {
    {
      float4 v0 = make_float4(0.f, 0.f, 0.f, 0.f);
      float4 v1 = make_float4(0.f, 0.f, 0.f, 0.f);
      if (m0 + ar < M) {
        const float* ap = &A[(size_t)(m0 + ar) * IN_F + k0 + ak];
        v0 = *(const float4*)ap;
        v1 = *(const float4*)(ap + 4);
      }
      union { ushort s[8]; uint4 v; } u;
      u.s[0] = f2bf(v0.x); u.s[1] = f2bf(v0.y);
      u.s[2] = f2bf(v0.z); u.s[3] = f2bf(v0.w);
      u.s[4] = f2bf(v1.x); u.s[5] = f2bf(v1.y);
      u.s[6] = f2bf(v1.z); u.s[7] = f2bf(v1.w);
      *(uint4*)&As[ar * LDA + ak] = u.v;
    }
#pragma unroll
    for (int i = 0; i < 4; ++i) {
      const int n = br + i * 64;
      *(uint4*)&Bs[n * LDA + bk] =
          *(const uint4*)&Bt[(size_t)n * IN_F + k0 + bk];
    }
    __syncthreads();

    bf16x8 aF[4], bF[4];
#pragma unroll
    for (int i = 0; i < 4; ++i)
      aF[i] = *(const bf16x8*)&As[(i * 16 + l16) * LDA + q * 8];
#pragma unroll
    for (int jj = 0; jj < 4; ++jj)
      bF[jj] = *(const bf16x8*)&Bs[(wn + jj * 16 + l16) * LDA + q * 8];
#pragma unroll
    for (int i = 0; i < 4; ++i)
#pragma unroll
      for (int jj = 0; jj < 4; ++jj)
        acc[i][jj] = __builtin_amdgcn_mfma_f32_16x16x32_bf16(
            aF[i], bF[jj], acc[i][jj], 0, 0, 0);
    __syncthreads();
  }

#pragma unroll
  for (int i = 0; i < 4; ++i) {
#pragma unroll
    for (int r = 0; r < 4; ++r) {
      const int row = m0 + 16 * i + q * 4 + r;
      if (row < M) {
#pragma unroll
        for (int jj = 0; jj < 4; ++jj) {
          const int col = wn + 16 * jj + l16;
          Cb[(size_t)row * HF + col] = f2bf(acc[i][jj][r]);
        }
      }
    }
  }
}

// ---------------------------------------------------------------------------
// Kernel 3: el[n,h] = sum_k feat[n,k] * wl[k,h]  (exact fp32, same FP order)
// wl staged transposed [h][k] (+4 pad) -> conflict-free ds_read_b128.
// ---------------------------------------------------------------------------
__global__ __launch_bounds__(256) void el_kernel(
    const float* __restrict__ feat, const float* __restrict__ wl,
    float* __restrict__ el, int NH) {
  __shared__ __align__(16) float wlsT[HEADS][IN_F + 4];
  const int t = threadIdx.x;
#pragma unroll
  for (int i = 0; i < (IN_F * HEADS) / 256; ++i) {
    const int idx = i * 256 + t;
    wlsT[idx & 7][idx >> 3] = wl[idx];
  }
  __syncthreads();

  const int idx = blockIdx.x * 256 + t;
  if (idx >= NH) return;
  const int n = idx >> 3;
  const int h = idx & 7;
  const float* fp = &feat[(size_t)n * IN_F];
  const float* wp = &wlsT[h][0];
  float acc = 0.f;
#pragma unroll 8
  for (int k0 = 0; k0 < IN_F; k0 += 4) {
    float4 v = *(const float4*)&fp[k0];
    float4 w = *(const float4*)&wp[k0];
    acc += v.x * w.x + v.y * w.y + v.z * w.z + v.w * w.w;
  }
  el[idx] = acc;
}

// ---------------------------------------------------------------------------
// Kernel 5: per-destination softmax + weighted aggregation.
// Fast path (deg <= 64, ~always at avg degree 16): featb gather rows are
// prefetched into registers at block start (<=16 uint2/wave, wave-uniform
// predication) so gather latency hides under the score phase; el is loaded
// once and kept in registers for both max and coeff. 3 barriers total.
// General path (deg > 64): verified round-1 chunked structure.
// ---------------------------------------------------------------------------
__global__ __launch_bounds__(256) void aggregate_kernel(
    const ushort* __restrict__ featb, const float* __restrict__ el,
    const int* __restrict__ src, const int* __restrict__ row_ptr,
    float* __restrict__ out) {
  const int v = blockIdx.x;
  const int t = threadIdx.x;
  const int beg = row_ptr[v];
  const int deg = row_ptr[v + 1] - beg;

  if (deg == 0) {  // segment_sum over empty segment = 0
    out[(size_t)v * HF + t] = 0.f;
    return;
  }

  __shared__ float s_wred[8][HEADS];                 // [0..3] max, [4..7] sum
  __shared__ __align__(16) float s_alpha[64][HEADS];
  __shared__ int s_src[64];
  __shared__ __align__(16) float s_out[4][HF];

  const int lane = t & 63;
  const int wave = t >> 6;
  const int j = t >> 3;        // 0..31: edge slot for score phases
  const int h8 = t & 7;        // head for score phases
  const int h = lane >> 3;     // head for gather (features lane*4..lane*4+3)

  float4 acc = make_float4(0.f, 0.f, 0.f, 0.f);
  float ssum = 0.f;

  if (deg <= 64) {
    // ---------------- fast path ----------------
    const int nIter = (deg > wave) ? ((deg - wave + 3) >> 2) : 0;  // wave-uniform
    uint2 q[16];
    // Prefetch gather rows: edge e = wave + 4*i, identical order to round 1.
#pragma unroll
    for (int i = 0; i < 16; ++i) {
      if (i < nIter) {
        const int s = src[beg + wave + 4 * i];
        q[i] = *(const uint2*)&featb[(size_t)s * HF + lane * 4];
      }
    }
    // Score phase: load el once, keep in regs for max AND coeff.
    float v1 = 0.f, v2 = 0.f;
    float mx = -1e30f;
    if (j < deg) {
      v1 = el[(size_t)src[beg + j] * HEADS + h8];
      mx = v1;
    }
    if (j + 32 < deg) {
      v2 = el[(size_t)src[beg + j + 32] * HEADS + h8];
      mx = fmaxf(mx, v2);
    }
    mx = fmaxf(mx, __shfl_xor(mx, 8));
    mx = fmaxf(mx, __shfl_xor(mx, 16));
    mx = fmaxf(mx, __shfl_xor(mx, 32));
    if (lane < HEADS) s_wred[wave][lane] = mx;
    __syncthreads();
    const float m = fmaxf(fmaxf(s_wred[0][h8], s_wred[1][h8]),
                          fmaxf(s_wred[2][h8], s_wred[3][h8]));
    if (j < deg) {
      const float z = v1 - m;
      const float w = (z >= 0.f) ? z : SLOPE * z;
      const float cf = __expf(w);
      s_alpha[j][h8] = cf;
      ssum += cf;
    }
    if (j + 32 < deg) {
      const float z = v2 - m;
      const float w = (z >= 0.f) ? z : SLOPE * z;
      const float cf = __expf(w);
      s_alpha[j + 32][h8] = cf;
      ssum += cf;
    }
    __syncthreads();
    // Consume prefetched rows (only real edges -> pad alphas never read).
#pragma unroll
    for (int i = 0; i < 16; ++i) {
      if (i < nIter) {
        const float a = s_alpha[wave + 4 * i][h];
        acc.x = fmaf(a, bf2f_lo(q[i].x), acc.x);
        acc.y = fmaf(a, bf2f_hi(q[i].x), acc.y);
        acc.z = fmaf(a, bf2f_lo(q[i].y), acc.z);
        acc.w = fmaf(a, bf2f_hi(q[i].y), acc.w);
      }
    }
  } else {
    // ---------------- general path (deg > 64) ----------------
    float mx = -1e30f;
    for (int e = j; e < deg; e += 32)
      mx = fmaxf(mx, el[(size_t)src[beg + e] * HEADS + h8]);
    mx = fmaxf(mx, __shfl_xor(mx, 8));
    mx = fmaxf(mx, __shfl_xor(mx, 16));
    mx = fmaxf(mx, __shfl_xor(mx, 32));
    if (lane < HEADS) s_wred[wave][lane] = mx;
    __syncthreads();
    const float m = fmaxf(fmaxf(s_wred[0][h8], s_wred[1][h8]),
                          fmaxf(s_wred[2][h8], s_wred[3][h8]));

    for (int c0 = 0; c0 < deg; c0 += 64) {
      const int cn = min(64, deg - c0);
      const int cnp = (cn + 3) & ~3;
      __syncthreads();  // protect s_alpha/s_src from previous iteration
      for (int cc = j; cc < cnp; cc += 32) {
        if (cc < cn) {
          const int s = src[beg + c0 + cc];
          if (h8 == 0) s_src[cc] = s;
          const float z = el[(size_t)s * HEADS + h8] - m;
          const float w = (z >= 0.f) ? z : SLOPE * z;
          const float cf = __expf(w);
          s_alpha[cc][h8] = cf;
          ssum += cf;
        } else {
          if (h8 == 0) s_src[cc] = 0;
          s_alpha[cc][h8] = 0.f;
        }
      }
      __syncthreads();
#pragma unroll 2
      for (int e0 = 0; e0 < cnp; e0 += 4) {
        const int e = e0 + wave;
        const int s = s_src[e];
        const float a = s_alpha[e][h];
        const uint2 u = *(const uint2*)&featb[(size_t)s * HF + lane * 4];
        acc.x = fmaf(a, bf2f_lo(u.x), acc.x);
        acc.y = fmaf(a, bf2f_hi(u.x), acc.y);
        acc.z = fmaf(a, bf2f_lo(u.y), acc.z);
        acc.w = fmaf(a, bf2f_hi(u.y), acc.w);
      }
    }
  }

  // ---------------- common tail ----------------
  ssum += __shfl_xor(ssum, 8);
  ssum += __shfl_xor(ssum, 16);
  ssum += __shfl_xor(ssum, 32);
  if (lane < HEADS) s_wred[4 + wave][lane] = ssum;
  *(float4*)&s_out[wave][lane * 4] = acc;
  __syncthreads();

  const int ho = t >> 5;
  const float ssum_all =
      s_wred[4][ho] + s_wred[5][ho] + s_wred[6][ho] + s_wred[7][ho];
  const float r = s_out[0][t] + s_out[1][t] + s_out[2][t] + s_out[3][t];
  out[(size_t)v * HF + t] = r / ssum_all;
}

// ---------------------------------------------------------------------------
extern "C" void kernel_launch(void* const* d_in, const int* in_sizes, int n_in,
                              void* d_out, int out_size, void* d_ws,
                              size_t ws_size, hipStream_t stream) {
  const float* feat = (const float*)d_in[0];
  const float* fc_w = (const float*)d_in[1];
  const float* attn_l = (const float*)d_in[2];
  // d_in[3] = attn_r: unused — cancels exactly in the edge softmax.
  const int* src = (const int*)d_in[4];
  const int* dst = (const int*)d_in[5];
  float* out = (float*)d_out;

  const int N = N_NODES;

  // workspace layout (16B-aligned sections)
  ushort* featb = (ushort*)d_ws;                       // N*256 bf16 (25.6 MB)
  float* el = (float*)(featb + (size_t)N * HF);        // N*8 f32
  float* wl = el + (size_t)N * HEADS;                  // 256*8 f32
  ushort* Bt = (ushort*)(wl + IN_F * HEADS);           // 256*256 bf16 (128 KB)
  int* row_ptr = (int*)(Bt + (size_t)IN_F * HF);       // N+1 ints

  prep_kernel<<<65 + ROWPTR_BLOCKS, 256, 0, stream>>>(fc_w, attn_l, Bt, wl,
                                                      dst, row_ptr);

  gemm_mfma<<<(N + BM - 1) / BM, 256, 0, stream>>>(feat, Bt, featb, N);

  el_kernel<<<(N * HEADS + 255) / 256, 256, 0, stream>>>(feat, wl, el,
                                                         N * HEADS);

  aggregate_kernel<<<N, 256, 0, stream>>>(featb, el, src, row_ptr, out);
}

// Round 3
// 234.999 us; speedup vs baseline: 1.1245x; 1.1245x over previous
//
#include <hip/hip_runtime.h>
#include <hip/hip_bf16.h>

#define N_NODES 50000
#define N_EDGES 800000
#define IN_F 256
#define HEADS 8
#define OUT_F 32
#define HF (HEADS * OUT_F)   // 256
#define SLOPE 0.2f

typedef __attribute__((ext_vector_type(8))) short bf16x8;
typedef __attribute__((ext_vector_type(4))) float f32x4;

__device__ __forceinline__ ushort f2bf(float f) {
  union { float f; unsigned u; } x;
  x.f = f;
  unsigned r = x.u + 0x7FFFu + ((x.u >> 16) & 1u);  // RNE
  return (ushort)(r >> 16);
}

__device__ __forceinline__ float bf2f_lo(unsigned u) {
  return __uint_as_float(u << 16);
}
__device__ __forceinline__ float bf2f_hi(unsigned u) {
  return __uint_as_float(u & 0xFFFF0000u);
}

// ---------------------------------------------------------------------------
// Kernel P: fused prep. blocks 0..63: Bt transpose+convert; block 64: wl;
// blocks 65..: CSR row_ptr binary search. All three are independent.
// ---------------------------------------------------------------------------
#define ROWPTR_BLOCKS ((N_NODES + 1 + 255) / 256)

__global__ __launch_bounds__(256) void prep_kernel(
    const float* __restrict__ fc_w, const float* __restrict__ attn_l,
    ushort* __restrict__ Bt, float* __restrict__ wl,
    const int* __restrict__ dst, int* __restrict__ row_ptr) {
  __shared__ float tile[32][33];
  const int b = blockIdx.x;
  const int t = threadIdx.x;

  if (b < 64) {
    // --- Bt[n][k] = bf16(fc_w[k][n]), 32x32 tile
    const int bx = (b & 7) * 32;   // n block
    const int by = (b >> 3) * 32;  // k block
    const int tx = t & 31;
    const int ty = t >> 5;  // 0..7
#pragma unroll
    for (int i = 0; i < 32; i += 8)
      tile[ty + i][tx] = fc_w[(size_t)(by + ty + i) * HF + bx + tx];
    __syncthreads();
#pragma unroll
    for (int i = 0; i < 32; i += 8)
      Bt[(size_t)(bx + ty + i) * IN_F + by + tx] = f2bf(tile[tx][ty + i]);
  } else if (b == 64) {
    // --- wl[k,h] = sum_f fc_w[k, h*32+f] * attn_l[h,f]
#pragma unroll
    for (int ii = 0; ii < 8; ++ii) {
      const int idx = ii * 256 + t;  // 0..2047
      const int k = idx >> 3;
      const int h = idx & 7;
      const float* fp = &fc_w[(size_t)k * HF + h * OUT_F];
      const float* ap = &attn_l[h * OUT_F];
      float acc = 0.f;
#pragma unroll
      for (int f = 0; f < OUT_F; f += 4) {
        float4 a = *(const float4*)&fp[f];
        float4 bb = *(const float4*)&ap[f];
        acc += a.x * bb.x + a.y * bb.y + a.z * bb.z + a.w * bb.w;
      }
      wl[idx] = acc;
    }
  } else {
    // --- row_ptr
    const int i = (b - 65) * 256 + t;
    if (i <= N_NODES) {
      int lo = 0, hi = N_EDGES;
      while (lo < hi) {
        int mid = (lo + hi) >> 1;
        if (dst[mid] < i) lo = mid + 1; else hi = mid;
      }
      row_ptr[i] = lo;
    }
  }
}

// ---------------------------------------------------------------------------
// Kernel 1: bf16 MFMA GEMM  Cb[M,256](bf16) = A[M,256](f32) @ B[256,256]
// BM=64 x BN=256 tile, BK=32, 256 threads = 4 waves. Wave w owns cols w*64.
// ---------------------------------------------------------------------------
#define BM 64
#define BN 256
#define BK 32
#define LDA 40   // padded LDS row stride (bf16 elems): 80 B, 16B-aligned

__global__ __launch_bounds__(256) void gemm_mfma(
    const float* __restrict__ A, const ushort* __restrict__ Bt,
    ushort* __restrict__ Cb, int M) {
  __shared__ __align__(16) ushort As[BM * LDA];   // [m][k]  5 KB
  __shared__ __align__(16) ushort Bs[BN * LDA];   // [n][k] 20 KB

  const int t = threadIdx.x;
  const int wave = t >> 6;
  const int lane = t & 63;
  const int m0 = blockIdx.x * BM;

  const int ar = t >> 2;
  const int ak = (t & 3) * 8;
  const int br = t >> 2;
  const int bk = (t & 3) * 8;

  const int q = lane >> 4;
  const int l16 = lane & 15;
  const int wn = wave * 64;

  f32x4 acc[4][4] = {};

  for (int k0 = 0; k0 < IN_F; k0 += BK) {
    {
      float4 v0 = make_float4(0.f, 0.f, 0.f, 0.f);
      float4 v1 = make_float4(0.f, 0.f, 0.f, 0.f);
      if (m0 + ar < M) {
        const float* ap = &A[(size_t)(m0 + ar) * IN_F + k0 + ak];
        v0 = *(const float4*)ap;
        v1 = *(const float4*)(ap + 4);
      }
      union { ushort s[8]; uint4 v; } u;
      u.s[0] = f2bf(v0.x); u.s[1] = f2bf(v0.y);
      u.s[2] = f2bf(v0.z); u.s[3] = f2bf(v0.w);
      u.s[4] = f2bf(v1.x); u.s[5] = f2bf(v1.y);
      u.s[6] = f2bf(v1.z); u.s[7] = f2bf(v1.w);
      *(uint4*)&As[ar * LDA + ak] = u.v;
    }
#pragma unroll
    for (int i = 0; i < 4; ++i) {
      const int n = br + i * 64;
      *(uint4*)&Bs[n * LDA + bk] =
          *(const uint4*)&Bt[(size_t)n * IN_F + k0 + bk];
    }
    __syncthreads();

    bf16x8 aF[4], bF[4];
#pragma unroll
    for (int i = 0; i < 4; ++i)
      aF[i] = *(const bf16x8*)&As[(i * 16 + l16) * LDA + q * 8];
#pragma unroll
    for (int jj = 0; jj < 4; ++jj)
      bF[jj] = *(const bf16x8*)&Bs[(wn + jj * 16 + l16) * LDA + q * 8];
#pragma unroll
    for (int i = 0; i < 4; ++i)
#pragma unroll
      for (int jj = 0; jj < 4; ++jj)
        acc[i][jj] = __builtin_amdgcn_mfma_f32_16x16x32_bf16(
            aF[i], bF[jj], acc[i][jj], 0, 0, 0);
    __syncthreads();
  }

#pragma unroll
  for (int i = 0; i < 4; ++i) {
#pragma unroll
    for (int r = 0; r < 4; ++r) {
      const int row = m0 + 16 * i + q * 4 + r;
      if (row < M) {
#pragma unroll
        for (int jj = 0; jj < 4; ++jj) {
          const int col = wn + 16 * jj + l16;
          Cb[(size_t)row * HF + col] = f2bf(acc[i][jj][r]);
        }
      }
    }
  }
}

// ---------------------------------------------------------------------------
// Kernel 3: el[n,h] = sum_k feat[n,k] * wl[k,h]  (round-1 verified version)
// ---------------------------------------------------------------------------
__global__ __launch_bounds__(256) void el_kernel(
    const float* __restrict__ feat, const float* __restrict__ wl,
    float* __restrict__ el, int NH) {
  __shared__ float wls[IN_F * HEADS];  // 8 KB
  const int t = threadIdx.x;
#pragma unroll
  for (int i = 0; i < (IN_F * HEADS) / 256; ++i)
    wls[i * 256 + t] = wl[i * 256 + t];
  __syncthreads();

  const int idx = blockIdx.x * 256 + t;
  if (idx >= NH) return;
  const int n = idx >> 3;
  const int h = idx & 7;
  const float* fp = &feat[(size_t)n * IN_F];
  float acc = 0.f;
#pragma unroll 8
  for (int k0 = 0; k0 < IN_F; k0 += 4) {
    float4 v = *(const float4*)&fp[k0];
    acc += v.x * wls[(k0 + 0) * 8 + h] + v.y * wls[(k0 + 1) * 8 + h] +
           v.z * wls[(k0 + 2) * 8 + h] + v.w * wls[(k0 + 3) * 8 + h];
  }
  el[idx] = acc;
}

// ---------------------------------------------------------------------------
// Kernel 5: per-destination softmax + weighted aggregation.
// WAVE-PER-NODE: 4 nodes per 256-thread block, zero barriers, zero LDS.
// Lane split: j = lane>>3 (edge slot 0..7), h8 = lane&7 (head for scores).
// Gather: lane c owns features 4c..4c+3, whose head is c>>3 == j.
// All cross-lane traffic is wave-internal shuffles.
// deg<=64 fast path: all src/el loads issued up-front (unrolled, static
// register arrays), then 8-edge gather passes with shfl broadcast of
// (alpha, src). deg>64 fallback streams passes of 8.
// ---------------------------------------------------------------------------
__global__ __launch_bounds__(256) void aggregate_kernel(
    const ushort* __restrict__ featb, const float* __restrict__ el,
    const int* __restrict__ src, const int* __restrict__ row_ptr,
    float* __restrict__ out) {
  const int t = threadIdx.x;
  const int wave = t >> 6;
  const int lane = t & 63;
  const int v = blockIdx.x * 4 + wave;   // N = 50000 = 12500*4 exactly

  const int beg = row_ptr[v];
  const int deg = row_ptr[v + 1] - beg;

  const int j = lane >> 3;   // edge slot (== gather head)
  const int h8 = lane & 7;   // head for score lanes

  float4 acc = make_float4(0.f, 0.f, 0.f, 0.f);

  if (deg == 0) {  // segment_sum over empty segment = 0
    *(float4*)&out[(size_t)v * HF + lane * 4] = acc;
    return;
  }

  float ssum = 0.f;

  if (deg <= 64) {
    // ---- load all src + el up front (<=16 independent loads in flight)
    const int npass = (deg + 7) >> 3;  // wave-uniform, 1..8
    int sidx[8];
    float vel[8];
    float mx = -1e30f;
#pragma unroll
    for (int p = 0; p < 8; ++p) {
      if (p < npass) {
        const int e = p * 8 + j;
        if (e < deg) {
          sidx[p] = src[beg + e];
          vel[p] = el[(size_t)sidx[p] * HEADS + h8];
        } else {
          sidx[p] = 0;
          vel[p] = -1e30f;
        }
        mx = fmaxf(mx, vel[p]);
      }
    }
    // per-head max across edge slots (bits 3..5)
    mx = fmaxf(mx, __shfl_xor(mx, 8));
    mx = fmaxf(mx, __shfl_xor(mx, 16));
    mx = fmaxf(mx, __shfl_xor(mx, 32));

    // ---- score + gather passes
#pragma unroll
    for (int p = 0; p < 8; ++p) {
      if (p < npass) {
        float cf = 0.f;
        if (p * 8 + j < deg) {
          const float z = vel[p] - mx;
          const float w = (z >= 0.f) ? z : SLOPE * z;
          cf = __expf(w);
        }
        ssum += cf;
        const int emax = min(8, deg - p * 8);  // wave-uniform
#pragma unroll
        for (int ee = 0; ee < 8; ++ee) {
          if (ee < emax) {
            const float a = __shfl(cf, ee * 8 + j);     // alpha[e][head=j]
            const int sb = __shfl(sidx[p], ee * 8);     // src of edge e
            const uint2 u =
                *(const uint2*)&featb[(size_t)sb * HF + lane * 4];
            acc.x = fmaf(a, bf2f_lo(u.x), acc.x);
            acc.y = fmaf(a, bf2f_hi(u.x), acc.y);
            acc.z = fmaf(a, bf2f_lo(u.y), acc.z);
            acc.w = fmaf(a, bf2f_hi(u.y), acc.w);
          }
        }
      }
    }
  } else {
    // ---- rare fallback: streamed passes of 8 edges
    float mx = -1e30f;
    for (int e = j; e < deg; e += 8)
      mx = fmaxf(mx, el[(size_t)src[beg + e] * HEADS + h8]);
    mx = fmaxf(mx, __shfl_xor(mx, 8));
    mx = fmaxf(mx, __shfl_xor(mx, 16));
    mx = fmaxf(mx, __shfl_xor(mx, 32));

    for (int p0 = 0; p0 < deg; p0 += 8) {
      float cf = 0.f;
      int sidx = 0;
      if (p0 + j < deg) {
        sidx = src[beg + p0 + j];
        const float z = el[(size_t)sidx * HEADS + h8] - mx;
        const float w = (z >= 0.f) ? z : SLOPE * z;
        cf = __expf(w);
      }
      ssum += cf;
      const int emax = min(8, deg - p0);  // wave-uniform
      for (int ee = 0; ee < emax; ++ee) {
        const float a = __shfl(cf, ee * 8 + j);
        const int sb = __shfl(sidx, ee * 8);
        const uint2 u = *(const uint2*)&featb[(size_t)sb * HF + lane * 4];
        acc.x = fmaf(a, bf2f_lo(u.x), acc.x);
        acc.y = fmaf(a, bf2f_hi(u.x), acc.y);
        acc.z = fmaf(a, bf2f_lo(u.y), acc.z);
        acc.w = fmaf(a, bf2f_hi(u.y), acc.w);
      }
    }
  }

  // ---- coeff-sum reduce over edge slots, broadcast head j's sum, normalize
  ssum += __shfl_xor(ssum, 8);
  ssum += __shfl_xor(ssum, 16);
  ssum += __shfl_xor(ssum, 32);
  const float inv = 1.0f / __shfl(ssum, j);  // lane j holds head-j sum (h8==j)
  acc.x *= inv; acc.y *= inv; acc.z *= inv; acc.w *= inv;
  *(float4*)&out[(size_t)v * HF + lane * 4] = acc;
}

// ---------------------------------------------------------------------------
extern "C" void kernel_launch(void* const* d_in, const int* in_sizes, int n_in,
                              void* d_out, int out_size, void* d_ws,
                              size_t ws_size, hipStream_t stream) {
  const float* feat = (const float*)d_in[0];
  const float* fc_w = (const float*)d_in[1];
  const float* attn_l = (const float*)d_in[2];
  // d_in[3] = attn_r: unused — cancels exactly in the edge softmax.
  const int* src = (const int*)d_in[4];
  const int* dst = (const int*)d_in[5];
  float* out = (float*)d_out;

  const int N = N_NODES;

  // workspace layout (16B-aligned sections)
  ushort* featb = (ushort*)d_ws;                       // N*256 bf16 (25.6 MB)
  float* el = (float*)(featb + (size_t)N * HF);        // N*8 f32
  float* wl = el + (size_t)N * HEADS;                  // 256*8 f32
  ushort* Bt = (ushort*)(wl + IN_F * HEADS);           // 256*256 bf16 (128 KB)
  int* row_ptr = (int*)(Bt + (size_t)IN_F * HF);       // N+1 ints

  prep_kernel<<<65 + ROWPTR_BLOCKS, 256, 0, stream>>>(fc_w, attn_l, Bt, wl,
                                                      dst, row_ptr);

  gemm_mfma<<<(N + BM - 1) / BM, 256, 0, stream>>>(feat, Bt, featb, N);

  el_kernel<<<(N * HEADS + 255) / 256, 256, 0, stream>>>(feat, wl, el,
                                                         N * HEADS);

  aggregate_kernel<<<N / 4, 256, 0, stream>>>(featb, el, src, row_ptr, out);
}

// Round 4
// 232.714 us; speedup vs baseline: 1.1355x; 1.0098x over previous
//
#include <hip/hip_runtime.h>
#include <hip/hip_bf16.h>

#define N_NODES 50000
#define N_EDGES 800000
#define IN_F 256
#define HEADS 8
#define OUT_F 32
#define HF (HEADS * OUT_F)   // 256
#define SLOPE 0.2f

typedef __attribute__((ext_vector_type(8))) short bf16x8;
typedef __attribute__((ext_vector_type(4))) float f32x4;

__device__ __forceinline__ ushort f2bf(float f) {
  union { float f; unsigned u; } x;
  x.f = f;
  unsigned r = x.u + 0x7FFFu + ((x.u >> 16) & 1u);  // RNE
  return (ushort)(r >> 16);
}

__device__ __forceinline__ float bf2f_lo(unsigned u) {
  return __uint_as_float(u << 16);
}
__device__ __forceinline__ float bf2f_hi(unsigned u) {
  return __uint_as_float(u & 0xFFFF0000u);
}

// ---------------------------------------------------------------------------
// Kernel P: fused prep. blocks 0..63: Bt transpose+convert; block 64: wl;
// blocks 65..: CSR row_ptr binary search. All three are independent.
// ---------------------------------------------------------------------------
#define ROWPTR_BLOCKS ((N_NODES + 1 + 255) / 256)

__global__ __launch_bounds__(256) void prep_kernel(
    const float* __restrict__ fc_w, const float* __restrict__ attn_l,
    ushort* __restrict__ Bt, float* __restrict__ wl,
    const int* __restrict__ dst, int* __restrict__ row_ptr) {
  __shared__ float tile[32][33];
  const int b = blockIdx.x;
  const int t = threadIdx.x;

  if (b < 64) {
    // --- Bt[n][k] = bf16(fc_w[k][n]), 32x32 tile
    const int bx = (b & 7) * 32;   // n block
    const int by = (b >> 3) * 32;  // k block
    const int tx = t & 31;
    const int ty = t >> 5;  // 0..7
#pragma unroll
    for (int i = 0; i < 32; i += 8)
      tile[ty + i][tx] = fc_w[(size_t)(by + ty + i) * HF + bx + tx];
    __syncthreads();
#pragma unroll
    for (int i = 0; i < 32; i += 8)
      Bt[(size_t)(bx + ty + i) * IN_F + by + tx] = f2bf(tile[tx][ty + i]);
  } else if (b == 64) {
    // --- wl[k,h] = sum_f fc_w[k, h*32+f] * attn_l[h,f]
#pragma unroll
    for (int ii = 0; ii < 8; ++ii) {
      const int idx = ii * 256 + t;  // 0..2047
      const int k = idx >> 3;
      const int h = idx & 7;
      const float* fp = &fc_w[(size_t)k * HF + h * OUT_F];
      const float* ap = &attn_l[h * OUT_F];
      float acc = 0.f;
#pragma unroll
      for (int f = 0; f < OUT_F; f += 4) {
        float4 a = *(const float4*)&fp[f];
        float4 bb = *(const float4*)&ap[f];
        acc += a.x * bb.x + a.y * bb.y + a.z * bb.z + a.w * bb.w;
      }
      wl[idx] = acc;
    }
  } else {
    // --- row_ptr
    const int i = (b - 65) * 256 + t;
    if (i <= N_NODES) {
      int lo = 0, hi = N_EDGES;
      while (lo < hi) {
        int mid = (lo + hi) >> 1;
        if (dst[mid] < i) lo = mid + 1; else hi = mid;
      }
      row_ptr[i] = lo;
    }
  }
}

// ---------------------------------------------------------------------------
// Kernel 1: bf16 MFMA GEMM  Cb[M,256](bf16) = A[M,256](f32) @ B[256,256]
// BM=64 x BN=256 tile, BK=32, 256 threads = 4 waves. Wave w owns cols w*64.
// ---------------------------------------------------------------------------
#define BM 64
#define BN 256
#define BK 32
#define LDA 40   // padded LDS row stride (bf16 elems): 80 B, 16B-aligned

__global__ __launch_bounds__(256) void gemm_mfma(
    const float* __restrict__ A, const ushort* __restrict__ Bt,
    ushort* __restrict__ Cb, int M) {
  __shared__ __align__(16) ushort As[BM * LDA];   // [m][k]  5 KB
  __shared__ __align__(16) ushort Bs[BN * LDA];   // [n][k] 20 KB

  const int t = threadIdx.x;
  const int wave = t >> 6;
  const int lane = t & 63;
  const int m0 = blockIdx.x * BM;

  const int ar = t >> 2;
  const int ak = (t & 3) * 8;
  const int br = t >> 2;
  const int bk = (t & 3) * 8;

  const int q = lane >> 4;
  const int l16 = lane & 15;
  const int wn = wave * 64;

  f32x4 acc[4][4] = {};

  for (int k0 = 0; k0 < IN_F; k0 += BK) {
    {
      float4 v0 = make_float4(0.f, 0.f, 0.f, 0.f);
      float4 v1 = make_float4(0.f, 0.f, 0.f, 0.f);
      if (m0 + ar < M) {
        const float* ap = &A[(size_t)(m0 + ar) * IN_F + k0 + ak];
        v0 = *(const float4*)ap;
        v1 = *(const float4*)(ap + 4);
      }
      union { ushort s[8]; uint4 v; } u;
      u.s[0] = f2bf(v0.x); u.s[1] = f2bf(v0.y);
      u.s[2] = f2bf(v0.z); u.s[3] = f2bf(v0.w);
      u.s[4] = f2bf(v1.x); u.s[5] = f2bf(v1.y);
      u.s[6] = f2bf(v1.z); u.s[7] = f2bf(v1.w);
      *(uint4*)&As[ar * LDA + ak] = u.v;
    }
#pragma unroll
    for (int i = 0; i < 4; ++i) {
      const int n = br + i * 64;
      *(uint4*)&Bs[n * LDA + bk] =
          *(const uint4*)&Bt[(size_t)n * IN_F + k0 + bk];
    }
    __syncthreads();

    bf16x8 aF[4], bF[4];
#pragma unroll
    for (int i = 0; i < 4; ++i)
      aF[i] = *(const bf16x8*)&As[(i * 16 + l16) * LDA + q * 8];
#pragma unroll
    for (int jj = 0; jj < 4; ++jj)
      bF[jj] = *(const bf16x8*)&Bs[(wn + jj * 16 + l16) * LDA + q * 8];
#pragma unroll
    for (int i = 0; i < 4; ++i)
#pragma unroll
      for (int jj = 0; jj < 4; ++jj)
        acc[i][jj] = __builtin_amdgcn_mfma_f32_16x16x32_bf16(
            aF[i], bF[jj], acc[i][jj], 0, 0, 0);
    __syncthreads();
  }

#pragma unroll
  for (int i = 0; i < 4; ++i) {
#pragma unroll
    for (int r = 0; r < 4; ++r) {
      const int row = m0 + 16 * i + q * 4 + r;
      if (row < M) {
#pragma unroll
        for (int jj = 0; jj < 4; ++jj) {
          const int col = wn + 16 * jj + l16;
          Cb[(size_t)row * HF + col] = f2bf(acc[i][jj][r]);
        }
      }
    }
  }
}

// ---------------------------------------------------------------------------
// Kernel 3: el[n,h] = sum_k feat[n,k] * wl[k,h]  (round-1 verified version)
// ---------------------------------------------------------------------------
__global__ __launch_bounds__(256) void el_kernel(
    const float* __restrict__ feat, const float* __restrict__ wl,
    float* __restrict__ el, int NH) {
  __shared__ float wls[IN_F * HEADS];  // 8 KB
  const int t = threadIdx.x;
#pragma unroll
  for (int i = 0; i < (IN_F * HEADS) / 256; ++i)
    wls[i * 256 + t] = wl[i * 256 + t];
  __syncthreads();

  const int idx = blockIdx.x * 256 + t;
  if (idx >= NH) return;
  const int n = idx >> 3;
  const int h = idx & 7;
  const float* fp = &feat[(size_t)n * IN_F];
  float acc = 0.f;
#pragma unroll 8
  for (int k0 = 0; k0 < IN_F; k0 += 4) {
    float4 v = *(const float4*)&fp[k0];
    acc += v.x * wls[(k0 + 0) * 8 + h] + v.y * wls[(k0 + 1) * 8 + h] +
           v.z * wls[(k0 + 2) * 8 + h] + v.w * wls[(k0 + 3) * 8 + h];
  }
  el[idx] = acc;
}

// ---------------------------------------------------------------------------
// Kernel 5: per-destination softmax + weighted aggregation.
// PERSISTENT WAVE-PER-NODE: 2048 blocks (8/CU co-resident), each wave owns
// ~7 consecutive nodes and software-pipelines across them:
//   iter top: issue row_ptr[v+1]      (hides under score phase)
//   after gather: issue src[v+1]      (hides under tail)
//   after tail-compute: issue el[v+1] (hides under store + next score)
// Fast path deg<=32 (99.98% of nodes): all scores in registers, unguarded
// 8-edge gather passes (pad edges carry cf=0 -> fmaf(0,x,acc) exact no-op,
// pad sidx=0 -> cached row-0 load). deg>32 falls to streaming path.
// Zero barriers, zero LDS. Accumulation order of real edges identical to
// round 3 (edge-ascending), so numerics are preserved.
// ---------------------------------------------------------------------------
#define AGG_BLOCKS 2048
#define AGG_WAVES (AGG_BLOCKS * 4)   // 8192
#define PER_WAVE ((N_NODES + AGG_WAVES - 1) / AGG_WAVES)  // 7

__global__ __launch_bounds__(256) void aggregate_kernel(
    const ushort* __restrict__ featb, const float* __restrict__ el,
    const int* __restrict__ src, const int* __restrict__ row_ptr,
    float* __restrict__ out) {
  const int t = threadIdx.x;
  const int wave = t >> 6;
  const int lane = t & 63;
  const int j = lane >> 3;   // edge slot / gather head
  const int h8 = lane & 7;   // head for score lanes
  const int wid = blockIdx.x * 4 + wave;

  int v = wid * PER_WAVE;
  const int vend = min(v + PER_WAVE, N_NODES);
  if (v >= vend) return;

  const ushort* fb_lane = featb + lane * 4;  // per-lane feature base

  // ---- prefetch state for the first node
  int beg = row_ptr[v];
  int deg = row_ptr[v + 1] - beg;
  int sidx[4];
  float vel[4];
  if (deg > 0 && deg <= 32) {
    const int npass = (deg + 7) >> 3;
#pragma unroll
    for (int p = 0; p < 4; ++p) {
      sidx[p] = 0;
      vel[p] = -1e30f;
      if (p < npass && p * 8 + j < deg) {
        sidx[p] = src[beg + p * 8 + j];
        vel[p] = el[(size_t)sidx[p] * HEADS + h8];
      }
    }
  }

  for (; v < vend; ++v) {
    const int vn = v + 1;
    // issue next row_ptr pair early
    int beg_n = 0, deg_n = 0;
    if (vn < vend) {
      beg_n = row_ptr[vn];
      deg_n = row_ptr[vn + 1] - beg_n;
    }

    float4 acc = make_float4(0.f, 0.f, 0.f, 0.f);
    float ssum = 0.f;
    int sidx_n[4];
    float vel_n[4];
    bool pfn = false;

    if (deg > 0 && deg <= 32) {
      // ---------------- fast path ----------------
      const int npass = (deg + 7) >> 3;  // wave-uniform 1..4
      // per-head max from prefetched scores
      float mx = fmaxf(fmaxf(vel[0], vel[1]), fmaxf(vel[2], vel[3]));
      mx = fmaxf(mx, __shfl_xor(mx, 8));
      mx = fmaxf(mx, __shfl_xor(mx, 16));
      mx = fmaxf(mx, __shfl_xor(mx, 32));

      // gather passes: 8 loads batched, then consume (unguarded inner)
#pragma unroll
      for (int p = 0; p < 4; ++p) {
        if (p < npass) {
          float cf = 0.f;
          if (p * 8 + j < deg) {
            const float z = vel[p] - mx;
            const float w = (z >= 0.f) ? z : SLOPE * z;
            cf = __expf(w);
          }
          ssum += cf;
          uint2 u[8];
#pragma unroll
          for (int ee = 0; ee < 8; ++ee) {
            const int sb = __shfl(sidx[p], ee * 8);  // readlane broadcast
            u[ee] = *(const uint2*)&fb_lane[(size_t)sb * HF];
          }
#pragma unroll
          for (int ee = 0; ee < 8; ++ee) {
            const float a = __shfl(cf, ee * 8 + j);  // alpha[e][head=j]
            acc.x = fmaf(a, bf2f_lo(u[ee].x), acc.x);
            acc.y = fmaf(a, bf2f_hi(u[ee].x), acc.y);
            acc.z = fmaf(a, bf2f_lo(u[ee].y), acc.z);
            acc.w = fmaf(a, bf2f_hi(u[ee].y), acc.w);
          }
        }
      }
    } else if (deg > 32) {
      // ---------------- streaming path (rare) ----------------
      float mx = -1e30f;
      for (int e = j; e < deg; e += 8)
        mx = fmaxf(mx, el[(size_t)src[beg + e] * HEADS + h8]);
      mx = fmaxf(mx, __shfl_xor(mx, 8));
      mx = fmaxf(mx, __shfl_xor(mx, 16));
      mx = fmaxf(mx, __shfl_xor(mx, 32));

      for (int p0 = 0; p0 < deg; p0 += 8) {
        float cf = 0.f;
        int sx = 0;
        if (p0 + j < deg) {
          sx = src[beg + p0 + j];
          const float z = el[(size_t)sx * HEADS + h8] - mx;
          const float w = (z >= 0.f) ? z : SLOPE * z;
          cf = __expf(w);
        }
        ssum += cf;
        const int emax = min(8, deg - p0);  // wave-uniform
        for (int ee = 0; ee < emax; ++ee) {
          const float a = __shfl(cf, ee * 8 + j);
          const int sb = __shfl(sx, ee * 8);
          const uint2 u = *(const uint2*)&fb_lane[(size_t)sb * HF];
          acc.x = fmaf(a, bf2f_lo(u.x), acc.x);
          acc.y = fmaf(a, bf2f_hi(u.x), acc.y);
          acc.z = fmaf(a, bf2f_lo(u.y), acc.z);
          acc.w = fmaf(a, bf2f_hi(u.y), acc.w);
        }
      }
    }
    // deg == 0: acc stays zero, ssum zero -> store zeros below.

    // ---- issue next node's src loads (hides under tail)
    int npass_n = 0;
    if (vn < vend && deg_n > 0 && deg_n <= 32) {
      pfn = true;
      npass_n = (deg_n + 7) >> 3;
#pragma unroll
      for (int p = 0; p < 4; ++p) {
        sidx_n[p] = 0;
        if (p < npass_n && p * 8 + j < deg_n)
          sidx_n[p] = src[beg_n + p * 8 + j];
      }
    }

    // ---- tail: coeff-sum reduce, normalize, store
    if (deg > 0) {
      ssum += __shfl_xor(ssum, 8);
      ssum += __shfl_xor(ssum, 16);
      ssum += __shfl_xor(ssum, 32);
      const float inv = 1.0f / __shfl(ssum, j);  // lane j holds head-j sum
      acc.x *= inv; acc.y *= inv; acc.z *= inv; acc.w *= inv;
    }
    *(float4*)&out[(size_t)v * HF + lane * 4] = acc;

    // ---- issue next node's el loads (hides under store + next score)
    if (pfn) {
#pragma unroll
      for (int p = 0; p < 4; ++p) {
        vel_n[p] = -1e30f;
        if (p < npass_n && p * 8 + j < deg_n)
          vel_n[p] = el[(size_t)sidx_n[p] * HEADS + h8];
      }
    }

    // ---- rotate pipeline state
    beg = beg_n;
    deg = (vn < vend) ? deg_n : 0;
#pragma unroll
    for (int p = 0; p < 4; ++p) {
      sidx[p] = pfn ? sidx_n[p] : 0;
      vel[p] = pfn ? vel_n[p] : -1e30f;
    }
  }
}

// ---------------------------------------------------------------------------
extern "C" void kernel_launch(void* const* d_in, const int* in_sizes, int n_in,
                              void* d_out, int out_size, void* d_ws,
                              size_t ws_size, hipStream_t stream) {
  const float* feat = (const float*)d_in[0];
  const float* fc_w = (const float*)d_in[1];
  const float* attn_l = (const float*)d_in[2];
  // d_in[3] = attn_r: unused — cancels exactly in the edge softmax.
  const int* src = (const int*)d_in[4];
  const int* dst = (const int*)d_in[5];
  float* out = (float*)d_out;

  const int N = N_NODES;

  // workspace layout (16B-aligned sections)
  ushort* featb = (ushort*)d_ws;                       // N*256 bf16 (25.6 MB)
  float* el = (float*)(featb + (size_t)N * HF);        // N*8 f32
  float* wl = el + (size_t)N * HEADS;                  // 256*8 f32
  ushort* Bt = (ushort*)(wl + IN_F * HEADS);           // 256*256 bf16 (128 KB)
  int* row_ptr = (int*)(Bt + (size_t)IN_F * HF);       // N+1 ints

  prep_kernel<<<65 + ROWPTR_BLOCKS, 256, 0, stream>>>(fc_w, attn_l, Bt, wl,
                                                      dst, row_ptr);

  gemm_mfma<<<(N + BM - 1) / BM, 256, 0, stream>>>(feat, Bt, featb, N);

  el_kernel<<<(N * HEADS + 255) / 256, 256, 0, stream>>>(feat, wl, el,
                                                         N * HEADS);

  aggregate_kernel<<<AGG_BLOCKS, 256, 0, stream>>>(featb, el, src, row_ptr,
                                                   out);
}

// Round 6
// 227.371 us; speedup vs baseline: 1.1622x; 1.0235x over previous
//
#include <hip/hip_runtime.h>
#include <hip/hip_bf16.h>

#define N_NODES 50000
#define N_EDGES 800000
#define IN_F 256
#define HEADS 8
#define OUT_F 32
#define HF (HEADS * OUT_F)   // 256
#define SLOPE 0.2f

typedef __attribute__((ext_vector_type(8))) short bf16x8;
typedef __attribute__((ext_vector_type(4))) float f32x4;

__device__ __forceinline__ ushort f2bf(float f) {
  union { float f; unsigned u; } x;
  x.f = f;
  unsigned r = x.u + 0x7FFFu + ((x.u >> 16) & 1u);  // RNE
  return (ushort)(r >> 16);
}

__device__ __forceinline__ float bf2f_lo(unsigned u) {
  return __uint_as_float(u << 16);
}
__device__ __forceinline__ float bf2f_hi(unsigned u) {
  return __uint_as_float(u & 0xFFFF0000u);
}

// ---------------------------------------------------------------------------
// Kernel P: fused prep. blocks 0..63: Bt transpose+convert; block 64: wl;
// blocks 65..: CSR row_ptr binary search. All three are independent.
// ---------------------------------------------------------------------------
#define ROWPTR_BLOCKS ((N_NODES + 1 + 255) / 256)

__global__ __launch_bounds__(256) void prep_kernel(
    const float* __restrict__ fc_w, const float* __restrict__ attn_l,
    ushort* __restrict__ Bt, float* __restrict__ wl,
    const int* __restrict__ dst, int* __restrict__ row_ptr) {
  __shared__ float tile[32][33];
  const int b = blockIdx.x;
  const int t = threadIdx.x;

  if (b < 64) {
    // --- Bt[n][k] = bf16(fc_w[k][n]), 32x32 tile
    const int bx = (b & 7) * 32;   // n block
    const int by = (b >> 3) * 32;  // k block
    const int tx = t & 31;
    const int ty = t >> 5;  // 0..7
#pragma unroll
    for (int i = 0; i < 32; i += 8)
      tile[ty + i][tx] = fc_w[(size_t)(by + ty + i) * HF + bx + tx];
    __syncthreads();
#pragma unroll
    for (int i = 0; i < 32; i += 8)
      Bt[(size_t)(bx + ty + i) * IN_F + by + tx] = f2bf(tile[tx][ty + i]);
  } else if (b == 64) {
    // --- wl[k,h] = sum_f fc_w[k, h*32+f] * attn_l[h,f]
#pragma unroll
    for (int ii = 0; ii < 8; ++ii) {
      const int idx = ii * 256 + t;  // 0..2047
      const int k = idx >> 3;
      const int h = idx & 7;
      const float* fp = &fc_w[(size_t)k * HF + h * OUT_F];
      const float* ap = &attn_l[h * OUT_F];
      float acc = 0.f;
#pragma unroll
      for (int f = 0; f < OUT_F; f += 4) {
        float4 a = *(const float4*)&fp[f];
        float4 bb = *(const float4*)&ap[f];
        acc += a.x * bb.x + a.y * bb.y + a.z * bb.z + a.w * bb.w;
      }
      wl[idx] = acc;
    }
  } else {
    // --- row_ptr
    const int i = (b - 65) * 256 + t;
    if (i <= N_NODES) {
      int lo = 0, hi = N_EDGES;
      while (lo < hi) {
        int mid = (lo + hi) >> 1;
        if (dst[mid] < i) lo = mid + 1; else hi = mid;
      }
      row_ptr[i] = lo;
    }
  }
}

// ---------------------------------------------------------------------------
// Kernel 1: bf16 MFMA GEMM + fused el.
// Cb[M,256](bf16) = A[M,256](f32) @ B[256,256];  el[M,8](f32) = A @ wl.
// BM=64 x BN=256 tile, BK=32, 256 threads = 4 waves. Wave w owns cols w*64.
// el uses the fp32 A values already staged per thread (8 k's of one row),
// wl from LDS; cross-thread reduce over the 4-thread row group at the end.
// el is fp32-exact (association change only vs separate el_kernel).
// ---------------------------------------------------------------------------
#define BM 64
#define BN 256
#define BK 32
#define LDA 40   // padded LDS row stride (bf16 elems): 80 B, 16B-aligned

__global__ __launch_bounds__(256) void gemm_mfma(
    const float* __restrict__ A, const ushort* __restrict__ Bt,
    const float* __restrict__ wl, ushort* __restrict__ Cb,
    float* __restrict__ el, int M) {
  __shared__ __align__(16) ushort As[BM * LDA];   // [m][k]  5 KB
  __shared__ __align__(16) ushort Bs[BN * LDA];   // [n][k] 20 KB
  __shared__ __align__(16) float wls[IN_F * HEADS];  // [k][h] 8 KB

  const int t = threadIdx.x;
  const int wave = t >> 6;
  const int lane = t & 63;
  const int m0 = blockIdx.x * BM;

  const int ar = t >> 2;         // A row 0..63
  const int ak = (t & 3) * 8;    // A k-offset {0,8,16,24}
  const int br = t >> 2;
  const int bk = (t & 3) * 8;

  const int q = lane >> 4;
  const int l16 = lane & 15;
  const int wn = wave * 64;

  // stage wl -> LDS (fenced by the first K-iteration's barrier)
#pragma unroll
  for (int i = 0; i < (IN_F * HEADS) / 256; ++i)
    wls[i * 256 + t] = wl[i * 256 + t];

  f32x4 acc[4][4] = {};
  float ela[8] = {0.f, 0.f, 0.f, 0.f, 0.f, 0.f, 0.f, 0.f};

  for (int k0 = 0; k0 < IN_F; k0 += BK) {
    float4 v0 = make_float4(0.f, 0.f, 0.f, 0.f);
    float4 v1 = make_float4(0.f, 0.f, 0.f, 0.f);
    {
      if (m0 + ar < M) {
        const float* ap = &A[(size_t)(m0 + ar) * IN_F + k0 + ak];
        v0 = *(const float4*)ap;
        v1 = *(const float4*)(ap + 4);
      }
      union { ushort s[8]; uint4 v; } u;
      u.s[0] = f2bf(v0.x); u.s[1] = f2bf(v0.y);
      u.s[2] = f2bf(v0.z); u.s[3] = f2bf(v0.w);
      u.s[4] = f2bf(v1.x); u.s[5] = f2bf(v1.y);
      u.s[6] = f2bf(v1.z); u.s[7] = f2bf(v1.w);
      *(uint4*)&As[ar * LDA + ak] = u.v;
    }
#pragma unroll
    for (int i = 0; i < 4; ++i) {
      const int n = br + i * 64;
      *(uint4*)&Bs[n * LDA + bk] =
          *(const uint4*)&Bt[(size_t)n * IN_F + k0 + bk];
    }
    __syncthreads();

    // --- fused el partial: this thread's 8 fp32 k-values x 8 heads
    {
      const float vv[8] = {v0.x, v0.y, v0.z, v0.w, v1.x, v1.y, v1.z, v1.w};
      const float* wrow = &wls[(k0 + ak) * HEADS];
#pragma unroll
      for (int kk = 0; kk < 8; ++kk) {
        const float4 wa = *(const float4*)&wrow[kk * 8];
        const float4 wb = *(const float4*)&wrow[kk * 8 + 4];
        ela[0] = fmaf(vv[kk], wa.x, ela[0]);
        ela[1] = fmaf(vv[kk], wa.y, ela[1]);
        ela[2] = fmaf(vv[kk], wa.z, ela[2]);
        ela[3] = fmaf(vv[kk], wa.w, ela[3]);
        ela[4] = fmaf(vv[kk], wb.x, ela[4]);
        ela[5] = fmaf(vv[kk], wb.y, ela[5]);
        ela[6] = fmaf(vv[kk], wb.z, ela[6]);
        ela[7] = fmaf(vv[kk], wb.w, ela[7]);
      }
    }

    bf16x8 aF[4], bF[4];
#pragma unroll
    for (int i = 0; i < 4; ++i)
      aF[i] = *(const bf16x8*)&As[(i * 16 + l16) * LDA + q * 8];
#pragma unroll
    for (int jj = 0; jj < 4; ++jj)
      bF[jj] = *(const bf16x8*)&Bs[(wn + jj * 16 + l16) * LDA + q * 8];
#pragma unroll
    for (int i = 0; i < 4; ++i)
#pragma unroll
      for (int jj = 0; jj < 4; ++jj)
        acc[i][jj] = __builtin_amdgcn_mfma_f32_16x16x32_bf16(
            aF[i], bF[jj], acc[i][jj], 0, 0, 0);
    __syncthreads();
  }

  // --- el reduce across the 4 threads sharing row ar (lanes t^1, t^2)
#pragma unroll
  for (int h = 0; h < 8; ++h) {
    ela[h] += __shfl_xor(ela[h], 1);
    ela[h] += __shfl_xor(ela[h], 2);
  }
  if ((t & 3) == 0 && m0 + ar < M) {
    *(float4*)&el[(size_t)(m0 + ar) * HEADS] =
        make_float4(ela[0], ela[1], ela[2], ela[3]);
    *(float4*)&el[(size_t)(m0 + ar) * HEADS + 4] =
        make_float4(ela[4], ela[5], ela[6], ela[7]);
  }

  // --- C epilogue: C/D layout col=l16, row=q*4+reg; store bf16
#pragma unroll
  for (int i = 0; i < 4; ++i) {
#pragma unroll
    for (int r = 0; r < 4; ++r) {
      const int row = m0 + 16 * i + q * 4 + r;
      if (row < M) {
#pragma unroll
        for (int jj = 0; jj < 4; ++jj) {
          const int col = wn + 16 * jj + l16;
          Cb[(size_t)row * HF + col] = f2bf(acc[i][jj][r]);
        }
      }
    }
  }
}

// ---------------------------------------------------------------------------
// Kernel 5: per-destination softmax + weighted aggregation.
// WAVE-PER-NODE (round-3 structure, proven 81.8 us), with gather batching
// DOUBLED to 16 in-flight uint2 loads per wave (pass pairs). If the 82-us
// plateau was per-wave miss-concurrency, this halves it; if it is a fabric
// wall, duration is unchanged and the floor is confirmed.
// Edge accumulation order unchanged (ascending), numerics preserved.
// ---------------------------------------------------------------------------
__global__ __launch_bounds__(256) void aggregate_kernel(
    const ushort* __restrict__ featb, const float* __restrict__ el,
    const int* __restrict__ src, const int* __restrict__ row_ptr,
    float* __restrict__ out) {
  const int t = threadIdx.x;
  const int wave = t >> 6;
  const int lane = t & 63;
  const int v = blockIdx.x * 4 + wave;   // N = 50000 = 12500*4 exactly

  const int beg = row_ptr[v];
  const int deg = row_ptr[v + 1] - beg;

  const int j = lane >> 3;   // edge slot (== gather head)
  const int h8 = lane & 7;   // head for score lanes

  float4 acc = make_float4(0.f, 0.f, 0.f, 0.f);

  if (deg == 0) {  // segment_sum over empty segment = 0
    *(float4*)&out[(size_t)v * HF + lane * 4] = acc;
    return;
  }

  const ushort* fb_lane = featb + lane * 4;
  float ssum = 0.f;

  if (deg <= 64) {
    const int npass = (deg + 7) >> 3;  // wave-uniform, 1..8
    int sidx[8];
    float vel[8];
#pragma unroll
    for (int p = 0; p < 8; ++p) {
      sidx[p] = 0;
      vel[p] = -1e30f;
      if (p < npass) {
        const int e = p * 8 + j;
        if (e < deg) {
          sidx[p] = src[beg + e];
          vel[p] = el[(size_t)sidx[p] * HEADS + h8];
        }
      }
    }
    float mx = -1e30f;
#pragma unroll
    for (int p = 0; p < 8; ++p) mx = fmaxf(mx, vel[p]);
    mx = fmaxf(mx, __shfl_xor(mx, 8));
    mx = fmaxf(mx, __shfl_xor(mx, 16));
    mx = fmaxf(mx, __shfl_xor(mx, 32));

    // ---- pass pairs: 16 gather loads in flight, then consume
#pragma unroll
    for (int p2 = 0; p2 < 8; p2 += 2) {
      if (p2 < npass) {
        float cf0 = 0.f, cf1 = 0.f;
        if (p2 * 8 + j < deg) {
          const float z = vel[p2] - mx;
          const float w = (z >= 0.f) ? z : SLOPE * z;
          cf0 = __expf(w);
        }
        if ((p2 + 1) * 8 + j < deg) {  // implies p2+1 < npass
          const float z = vel[p2 + 1] - mx;
          const float w = (z >= 0.f) ? z : SLOPE * z;
          cf1 = __expf(w);
        }
        ssum += cf0 + cf1;
        uint2 u[16];
#pragma unroll
        for (int ee = 0; ee < 8; ++ee) {
          const int sb = __shfl(sidx[p2], ee * 8);
          u[ee] = *(const uint2*)&fb_lane[(size_t)sb * HF];
        }
#pragma unroll
        for (int ee = 0; ee < 8; ++ee) {
          const int sb = __shfl(sidx[p2 + 1], ee * 8);  // 0 if pad -> row 0
          u[8 + ee] = *(const uint2*)&fb_lane[(size_t)sb * HF];
        }
#pragma unroll
        for (int ee = 0; ee < 8; ++ee) {
          const float a = __shfl(cf0, ee * 8 + j);
          acc.x = fmaf(a, bf2f_lo(u[ee].x), acc.x);
          acc.y = fmaf(a, bf2f_hi(u[ee].x), acc.y);
          acc.z = fmaf(a, bf2f_lo(u[ee].y), acc.z);
          acc.w = fmaf(a, bf2f_hi(u[ee].y), acc.w);
        }
#pragma unroll
        for (int ee = 0; ee < 8; ++ee) {
          const float a = __shfl(cf1, ee * 8 + j);  // 0 for pads: exact no-op
          acc.x = fmaf(a, bf2f_lo(u[8 + ee].x), acc.x);
          acc.y = fmaf(a, bf2f_hi(u[8 + ee].x), acc.y);
          acc.z = fmaf(a, bf2f_lo(u[8 + ee].y), acc.z);
          acc.w = fmaf(a, bf2f_hi(u[8 + ee].y), acc.w);
        }
      }
    }
  } else {
    // ---- rare fallback: streamed passes of 8 edges
    float mx = -1e30f;
    for (int e = j; e < deg; e += 8)
      mx = fmaxf(mx, el[(size_t)src[beg + e] * HEADS + h8]);
    mx = fmaxf(mx, __shfl_xor(mx, 8));
    mx = fmaxf(mx, __shfl_xor(mx, 16));
    mx = fmaxf(mx, __shfl_xor(mx, 32));

    for (int p0 = 0; p0 < deg; p0 += 8) {
      float cf = 0.f;
      int sx = 0;
      if (p0 + j < deg) {
        sx = src[beg + p0 + j];
        const float z = el[(size_t)sx * HEADS + h8] - mx;
        const float w = (z >= 0.f) ? z : SLOPE * z;
        cf = __expf(w);
      }
      ssum += cf;
      const int emax = min(8, deg - p0);  // wave-uniform
      for (int ee = 0; ee < emax; ++ee) {
        const float a = __shfl(cf, ee * 8 + j);
        const int sb = __shfl(sx, ee * 8);
        const uint2 u = *(const uint2*)&fb_lane[(size_t)sb * HF];
        acc.x = fmaf(a, bf2f_lo(u.x), acc.x);
        acc.y = fmaf(a, bf2f_hi(u.x), acc.y);
        acc.z = fmaf(a, bf2f_lo(u.y), acc.z);
        acc.w = fmaf(a, bf2f_hi(u.y), acc.w);
      }
    }
  }

  // ---- coeff-sum reduce over edge slots, broadcast head j's sum, normalize
  ssum += __shfl_xor(ssum, 8);
  ssum += __shfl_xor(ssum, 16);
  ssum += __shfl_xor(ssum, 32);
  const float inv = 1.0f / __shfl(ssum, j);  // lane j holds head-j sum (h8==j)
  acc.x *= inv; acc.y *= inv; acc.z *= inv; acc.w *= inv;
  *(float4*)&out[(size_t)v * HF + lane * 4] = acc;
}

// ---------------------------------------------------------------------------
extern "C" void kernel_launch(void* const* d_in, const int* in_sizes, int n_in,
                              void* d_out, int out_size, void* d_ws,
                              size_t ws_size, hipStream_t stream) {
  const float* feat = (const float*)d_in[0];
  const float* fc_w = (const float*)d_in[1];
  const float* attn_l = (const float*)d_in[2];
  // d_in[3] = attn_r: unused — cancels exactly in the edge softmax.
  const int* src = (const int*)d_in[4];
  const int* dst = (const int*)d_in[5];
  float* out = (float*)d_out;

  const int N = N_NODES;

  // workspace layout (16B-aligned sections)
  ushort* featb = (ushort*)d_ws;                       // N*256 bf16 (25.6 MB)
  float* el = (float*)(featb + (size_t)N * HF);        // N*8 f32
  float* wl = el + (size_t)N * HEADS;                  // 256*8 f32
  ushort* Bt = (ushort*)(wl + IN_F * HEADS);           // 256*256 bf16 (128 KB)
  int* row_ptr = (int*)(Bt + (size_t)IN_F * HF);       // N+1 ints

  prep_kernel<<<65 + ROWPTR_BLOCKS, 256, 0, stream>>>(fc_w, attn_l, Bt, wl,
                                                      dst, row_ptr);

  gemm_mfma<<<(N + BM - 1) / BM, 256, 0, stream>>>(feat, Bt, wl, featb, el,
                                                   N);

  aggregate_kernel<<<N / 4, 256, 0, stream>>>(featb, el, src, row_ptr, out);
}

// Round 7
// 222.924 us; speedup vs baseline: 1.1854x; 1.0200x over previous
//
#include <hip/hip_runtime.h>
#include <hip/hip_bf16.h>

#define N_NODES 50000
#define N_EDGES 800000
#define IN_F 256
#define HEADS 8
#define OUT_F 32
#define HF (HEADS * OUT_F)   // 256
#define SLOPE 0.2f

typedef __attribute__((ext_vector_type(8))) short bf16x8;
typedef __attribute__((ext_vector_type(4))) float f32x4;

__device__ __forceinline__ ushort f2bf(float f) {
  union { float f; unsigned u; } x;
  x.f = f;
  unsigned r = x.u + 0x7FFFu + ((x.u >> 16) & 1u);  // RNE
  return (ushort)(r >> 16);
}

__device__ __forceinline__ float bf2f_lo(unsigned u) {
  return __uint_as_float(u << 16);
}
__device__ __forceinline__ float bf2f_hi(unsigned u) {
  return __uint_as_float(u & 0xFFFF0000u);
}

// ---------------------------------------------------------------------------
// Kernel P: fused prep. blocks 0..63: Bt transpose+convert; block 64: wl;
// blocks 65..: CSR row_ptr binary search. All three are independent.
// ---------------------------------------------------------------------------
#define ROWPTR_BLOCKS ((N_NODES + 1 + 255) / 256)

__global__ __launch_bounds__(256) void prep_kernel(
    const float* __restrict__ fc_w, const float* __restrict__ attn_l,
    ushort* __restrict__ Bt, float* __restrict__ wl,
    const int* __restrict__ dst, int* __restrict__ row_ptr) {
  __shared__ float tile[32][33];
  const int b = blockIdx.x;
  const int t = threadIdx.x;

  if (b < 64) {
    // --- Bt[n][k] = bf16(fc_w[k][n]), 32x32 tile
    const int bx = (b & 7) * 32;   // n block
    const int by = (b >> 3) * 32;  // k block
    const int tx = t & 31;
    const int ty = t >> 5;  // 0..7
#pragma unroll
    for (int i = 0; i < 32; i += 8)
      tile[ty + i][tx] = fc_w[(size_t)(by + ty + i) * HF + bx + tx];
    __syncthreads();
#pragma unroll
    for (int i = 0; i < 32; i += 8)
      Bt[(size_t)(bx + ty + i) * IN_F + by + tx] = f2bf(tile[tx][ty + i]);
  } else if (b == 64) {
    // --- wl[k,h] = sum_f fc_w[k, h*32+f] * attn_l[h,f]
#pragma unroll
    for (int ii = 0; ii < 8; ++ii) {
      const int idx = ii * 256 + t;  // 0..2047
      const int k = idx >> 3;
      const int h = idx & 7;
      const float* fp = &fc_w[(size_t)k * HF + h * OUT_F];
      const float* ap = &attn_l[h * OUT_F];
      float acc = 0.f;
#pragma unroll
      for (int f = 0; f < OUT_F; f += 4) {
        float4 a = *(const float4*)&fp[f];
        float4 bb = *(const float4*)&ap[f];
        acc += a.x * bb.x + a.y * bb.y + a.z * bb.z + a.w * bb.w;
      }
      wl[idx] = acc;
    }
  } else {
    // --- row_ptr
    const int i = (b - 65) * 256 + t;
    if (i <= N_NODES) {
      int lo = 0, hi = N_EDGES;
      while (lo < hi) {
        int mid = (lo + hi) >> 1;
        if (dst[mid] < i) lo = mid + 1; else hi = mid;
      }
      row_ptr[i] = lo;
    }
  }
}

// ---------------------------------------------------------------------------
// Kernel 1: bf16 MFMA GEMM  Cb[M,256](bf16) = A[M,256](f32) @ B[256,256]
// BM=64 x BN=256 tile, BK=32, 256 threads = 4 waves. Wave w owns cols w*64.
// (el fusion reverted: it added ~150cyc/K-step VALU+LDS to an 80cyc MFMA
//  phase — cost more inside the GEMM than the separate el_kernel.)
// ---------------------------------------------------------------------------
#define BM 64
#define BN 256
#define BK 32
#define LDA 40   // padded LDS row stride (bf16 elems): 80 B, 16B-aligned

__global__ __launch_bounds__(256) void gemm_mfma(
    const float* __restrict__ A, const ushort* __restrict__ Bt,
    ushort* __restrict__ Cb, int M) {
  __shared__ __align__(16) ushort As[BM * LDA];   // [m][k]  5 KB
  __shared__ __align__(16) ushort Bs[BN * LDA];   // [n][k] 20 KB

  const int t = threadIdx.x;
  const int wave = t >> 6;
  const int lane = t & 63;
  const int m0 = blockIdx.x * BM;

  const int ar = t >> 2;
  const int ak = (t & 3) * 8;
  const int br = t >> 2;
  const int bk = (t & 3) * 8;

  const int q = lane >> 4;
  const int l16 = lane & 15;
  const int wn = wave * 64;

  f32x4 acc[4][4] = {};

  for (int k0 = 0; k0 < IN_F; k0 += BK) {
    {
      float4 v0 = make_float4(0.f, 0.f, 0.f, 0.f);
      float4 v1 = make_float4(0.f, 0.f, 0.f, 0.f);
      if (m0 + ar < M) {
        const float* ap = &A[(size_t)(m0 + ar) * IN_F + k0 + ak];
        v0 = *(const float4*)ap;
        v1 = *(const float4*)(ap + 4);
      }
      union { ushort s[8]; uint4 v; } u;
      u.s[0] = f2bf(v0.x); u.s[1] = f2bf(v0.y);
      u.s[2] = f2bf(v0.z); u.s[3] = f2bf(v0.w);
      u.s[4] = f2bf(v1.x); u.s[5] = f2bf(v1.y);
      u.s[6] = f2bf(v1.z); u.s[7] = f2bf(v1.w);
      *(uint4*)&As[ar * LDA + ak] = u.v;
    }
#pragma unroll
    for (int i = 0; i < 4; ++i) {
      const int n = br + i * 64;
      *(uint4*)&Bs[n * LDA + bk] =
          *(const uint4*)&Bt[(size_t)n * IN_F + k0 + bk];
    }
    __syncthreads();

    bf16x8 aF[4], bF[4];
#pragma unroll
    for (int i = 0; i < 4; ++i)
      aF[i] = *(const bf16x8*)&As[(i * 16 + l16) * LDA + q * 8];
#pragma unroll
    for (int jj = 0; jj < 4; ++jj)
      bF[jj] = *(const bf16x8*)&Bs[(wn + jj * 16 + l16) * LDA + q * 8];
#pragma unroll
    for (int i = 0; i < 4; ++i)
#pragma unroll
      for (int jj = 0; jj < 4; ++jj)
        acc[i][jj] = __builtin_amdgcn_mfma_f32_16x16x32_bf16(
            aF[i], bF[jj], acc[i][jj], 0, 0, 0);
    __syncthreads();
  }

#pragma unroll
  for (int i = 0; i < 4; ++i) {
#pragma unroll
    for (int r = 0; r < 4; ++r) {
      const int row = m0 + 16 * i + q * 4 + r;
      if (row < M) {
#pragma unroll
        for (int jj = 0; jj < 4; ++jj) {
          const int col = wn + 16 * jj + l16;
          Cb[(size_t)row * HF + col] = f2bf(acc[i][jj][r]);
        }
      }
    }
  }
}

// ---------------------------------------------------------------------------
// Kernel 3: el[n,h] = sum_k feat[n,k] * wl[k,h]  (round-1 verified version)
// ---------------------------------------------------------------------------
__global__ __launch_bounds__(256) void el_kernel(
    const float* __restrict__ feat, const float* __restrict__ wl,
    float* __restrict__ el, int NH) {
  __shared__ float wls[IN_F * HEADS];  // 8 KB
  const int t = threadIdx.x;
#pragma unroll
  for (int i = 0; i < (IN_F * HEADS) / 256; ++i)
    wls[i * 256 + t] = wl[i * 256 + t];
  __syncthreads();

  const int idx = blockIdx.x * 256 + t;
  if (idx >= NH) return;
  const int n = idx >> 3;
  const int h = idx & 7;
  const float* fp = &feat[(size_t)n * IN_F];
  float acc = 0.f;
#pragma unroll 8
  for (int k0 = 0; k0 < IN_F; k0 += 4) {
    float4 v = *(const float4*)&fp[k0];
    acc += v.x * wls[(k0 + 0) * 8 + h] + v.y * wls[(k0 + 1) * 8 + h] +
           v.z * wls[(k0 + 2) * 8 + h] + v.w * wls[(k0 + 3) * 8 + h];
  }
  el[idx] = acc;
}

// ---------------------------------------------------------------------------
// Kernel 5: per-destination softmax + weighted aggregation.
// WAVE-PER-NODE, zero barriers/LDS. Fast path (deg<=64) round 7 change:
// the first 16 gather loads (which depend ONLY on sidx) are issued BEFORE
// the el score loads, so the whole score phase (scattered el loads +
// shuffle max + exp) hides under gather latency. For deg<=16 (~57% of
// nodes) ALL gathers are in flight during scoring. Remaining passes use
// the proven 16-deep pass-pair batching. Edge accumulation order and ssum
// association are bit-identical to round 6.
// ---------------------------------------------------------------------------
__global__ __launch_bounds__(256) void aggregate_kernel(
    const ushort* __restrict__ featb, const float* __restrict__ el,
    const int* __restrict__ src, const int* __restrict__ row_ptr,
    float* __restrict__ out) {
  const int t = threadIdx.x;
  const int wave = t >> 6;
  const int lane = t & 63;
  const int v = blockIdx.x * 4 + wave;   // N = 50000 = 12500*4 exactly

  const int beg = row_ptr[v];
  const int deg = row_ptr[v + 1] - beg;

  const int j = lane >> 3;   // edge slot (== gather head)
  const int h8 = lane & 7;   // head for score lanes

  float4 acc = make_float4(0.f, 0.f, 0.f, 0.f);

  if (deg == 0) {  // segment_sum over empty segment = 0
    *(float4*)&out[(size_t)v * HF + lane * 4] = acc;
    return;
  }

  const ushort* fb_lane = featb + lane * 4;
  float ssum = 0.f;

  if (deg <= 64) {
    const int npass = (deg + 7) >> 3;  // wave-uniform, 1..8

    // ---- 1. src indices (all passes)
    int sidx[8];
#pragma unroll
    for (int p = 0; p < 8; ++p) {
      sidx[p] = 0;
      if (p < npass) {
        const int e = p * 8 + j;
        if (e < deg) sidx[p] = src[beg + e];
      }
    }

    // ---- 2. issue first 16 gather loads NOW (independent of scores)
    uint2 u[16];
#pragma unroll
    for (int ee = 0; ee < 8; ++ee) {
      const int sb = __shfl(sidx[0], ee * 8);
      u[ee] = *(const uint2*)&fb_lane[(size_t)sb * HF];
    }
#pragma unroll
    for (int ee = 0; ee < 8; ++ee) {
      const int sb = __shfl(sidx[1], ee * 8);  // 0 if npass<2 -> row 0
      u[8 + ee] = *(const uint2*)&fb_lane[(size_t)sb * HF];
    }

    // ---- 3. score loads + max + coeffs (hidden under the gathers above)
    float vel[8];
#pragma unroll
    for (int p = 0; p < 8; ++p) {
      vel[p] = -1e30f;
      if (p < npass && p * 8 + j < deg)
        vel[p] = el[(size_t)sidx[p] * HEADS + h8];
    }
    float mx = -1e30f;
#pragma unroll
    for (int p = 0; p < 8; ++p) mx = fmaxf(mx, vel[p]);
    mx = fmaxf(mx, __shfl_xor(mx, 8));
    mx = fmaxf(mx, __shfl_xor(mx, 16));
    mx = fmaxf(mx, __shfl_xor(mx, 32));

    float cf[8];
#pragma unroll
    for (int p = 0; p < 8; ++p) {
      cf[p] = 0.f;
      if (p < npass && p * 8 + j < deg) {
        const float z = vel[p] - mx;
        const float w = (z >= 0.f) ? z : SLOPE * z;
        cf[p] = __expf(w);
      }
    }
    // ssum association identical to round 6 (per-pair sums)
#pragma unroll
    for (int p2 = 0; p2 < 8; p2 += 2)
      if (p2 < npass) ssum += cf[p2] + cf[p2 + 1];

    // ---- 4. consume passes 0,1 (already loaded)
#pragma unroll
    for (int ee = 0; ee < 8; ++ee) {
      const float a = __shfl(cf[0], ee * 8 + j);
      acc.x = fmaf(a, bf2f_lo(u[ee].x), acc.x);
      acc.y = fmaf(a, bf2f_hi(u[ee].x), acc.y);
      acc.z = fmaf(a, bf2f_lo(u[ee].y), acc.z);
      acc.w = fmaf(a, bf2f_hi(u[ee].y), acc.w);
    }
#pragma unroll
    for (int ee = 0; ee < 8; ++ee) {
      const float a = __shfl(cf[1], ee * 8 + j);  // 0 for pads: exact no-op
      acc.x = fmaf(a, bf2f_lo(u[8 + ee].x), acc.x);
      acc.y = fmaf(a, bf2f_hi(u[8 + ee].x), acc.y);
      acc.z = fmaf(a, bf2f_lo(u[8 + ee].y), acc.z);
      acc.w = fmaf(a, bf2f_hi(u[8 + ee].y), acc.w);
    }

    // ---- 5. remaining passes, 16-deep pass pairs (round-6 proven)
#pragma unroll
    for (int p2 = 2; p2 < 8; p2 += 2) {
      if (p2 < npass) {
#pragma unroll
        for (int ee = 0; ee < 8; ++ee) {
          const int sb = __shfl(sidx[p2], ee * 8);
          u[ee] = *(const uint2*)&fb_lane[(size_t)sb * HF];
        }
#pragma unroll
        for (int ee = 0; ee < 8; ++ee) {
          const int sb = __shfl(sidx[p2 + 1], ee * 8);
          u[8 + ee] = *(const uint2*)&fb_lane[(size_t)sb * HF];
        }
#pragma unroll
        for (int ee = 0; ee < 8; ++ee) {
          const float a = __shfl(cf[p2], ee * 8 + j);
          acc.x = fmaf(a, bf2f_lo(u[ee].x), acc.x);
          acc.y = fmaf(a, bf2f_hi(u[ee].x), acc.y);
          acc.z = fmaf(a, bf2f_lo(u[ee].y), acc.z);
          acc.w = fmaf(a, bf2f_hi(u[ee].y), acc.w);
        }
#pragma unroll
        for (int ee = 0; ee < 8; ++ee) {
          const float a = __shfl(cf[p2 + 1], ee * 8 + j);
          acc.x = fmaf(a, bf2f_lo(u[8 + ee].x), acc.x);
          acc.y = fmaf(a, bf2f_hi(u[8 + ee].x), acc.y);
          acc.z = fmaf(a, bf2f_lo(u[8 + ee].y), acc.z);
          acc.w = fmaf(a, bf2f_hi(u[8 + ee].y), acc.w);
        }
      }
    }
  } else {
    // ---- rare fallback: streamed passes of 8 edges
    float mx = -1e30f;
    for (int e = j; e < deg; e += 8)
      mx = fmaxf(mx, el[(size_t)src[beg + e] * HEADS + h8]);
    mx = fmaxf(mx, __shfl_xor(mx, 8));
    mx = fmaxf(mx, __shfl_xor(mx, 16));
    mx = fmaxf(mx, __shfl_xor(mx, 32));

    for (int p0 = 0; p0 < deg; p0 += 8) {
      float cf = 0.f;
      int sx = 0;
      if (p0 + j < deg) {
        sx = src[beg + p0 + j];
        const float z = el[(size_t)sx * HEADS + h8] - mx;
        const float w = (z >= 0.f) ? z : SLOPE * z;
        cf = __expf(w);
      }
      ssum += cf;
      const int emax = min(8, deg - p0);  // wave-uniform
      for (int ee = 0; ee < emax; ++ee) {
        const float a = __shfl(cf, ee * 8 + j);
        const int sb = __shfl(sx, ee * 8);
        const uint2 u2 = *(const uint2*)&fb_lane[(size_t)sb * HF];
        acc.x = fmaf(a, bf2f_lo(u2.x), acc.x);
        acc.y = fmaf(a, bf2f_hi(u2.x), acc.y);
        acc.z = fmaf(a, bf2f_lo(u2.y), acc.z);
        acc.w = fmaf(a, bf2f_hi(u2.y), acc.w);
      }
    }
  }

  // ---- coeff-sum reduce over edge slots, broadcast head j's sum, normalize
  ssum += __shfl_xor(ssum, 8);
  ssum += __shfl_xor(ssum, 16);
  ssum += __shfl_xor(ssum, 32);
  const float inv = 1.0f / __shfl(ssum, j);  // lane j holds head-j sum (h8==j)
  acc.x *= inv; acc.y *= inv; acc.z *= inv; acc.w *= inv;
  *(float4*)&out[(size_t)v * HF + lane * 4] = acc;
}

// ---------------------------------------------------------------------------
extern "C" void kernel_launch(void* const* d_in, const int* in_sizes, int n_in,
                              void* d_out, int out_size, void* d_ws,
                              size_t ws_size, hipStream_t stream) {
  const float* feat = (const float*)d_in[0];
  const float* fc_w = (const float*)d_in[1];
  const float* attn_l = (const float*)d_in[2];
  // d_in[3] = attn_r: unused — cancels exactly in the edge softmax.
  const int* src = (const int*)d_in[4];
  const int* dst = (const int*)d_in[5];
  float* out = (float*)d_out;

  const int N = N_NODES;

  // workspace layout (16B-aligned sections)
  ushort* featb = (ushort*)d_ws;                       // N*256 bf16 (25.6 MB)
  float* el = (float*)(featb + (size_t)N * HF);        // N*8 f32
  float* wl = el + (size_t)N * HEADS;                  // 256*8 f32
  ushort* Bt = (ushort*)(wl + IN_F * HEADS);           // 256*256 bf16 (128 KB)
  int* row_ptr = (int*)(Bt + (size_t)IN_F * HF);       // N+1 ints

  prep_kernel<<<65 + ROWPTR_BLOCKS, 256, 0, stream>>>(fc_w, attn_l, Bt, wl,
                                                      dst, row_ptr);

  gemm_mfma<<<(N + BM - 1) / BM, 256, 0, stream>>>(feat, Bt, featb, N);

  el_kernel<<<(N * HEADS + 255) / 256, 256, 0, stream>>>(feat, wl, el,
                                                         N * HEADS);

  aggregate_kernel<<<N / 4, 256, 0, stream>>>(featb, el, src, row_ptr, out);
}

// Round 8
// 219.847 us; speedup vs baseline: 1.2020x; 1.0140x over previous
//
#include <hip/hip_runtime.h>
#include <hip/hip_bf16.h>

#define N_NODES 50000
#define N_EDGES 800000
#define IN_F 256
#define HEADS 8
#define OUT_F 32
#define HF (HEADS * OUT_F)   // 256
#define SLOPE 0.2f

typedef __attribute__((ext_vector_type(8))) short bf16x8;
typedef __attribute__((ext_vector_type(4))) float f32x4;

__device__ __forceinline__ ushort f2bf(float f) {
  union { float f; unsigned u; } x;
  x.f = f;
  unsigned r = x.u + 0x7FFFu + ((x.u >> 16) & 1u);  // RNE
  return (ushort)(r >> 16);
}

__device__ __forceinline__ float bf2f_lo(unsigned u) {
  return __uint_as_float(u << 16);
}
__device__ __forceinline__ float bf2f_hi(unsigned u) {
  return __uint_as_float(u & 0xFFFF0000u);
}

// ---------------------------------------------------------------------------
// Kernel P: fused prep. blocks 0..63: Bt transpose+convert; block 64: wl;
// blocks 65..: CSR row_ptr binary search. All three are independent.
// ---------------------------------------------------------------------------
#define ROWPTR_BLOCKS ((N_NODES + 1 + 255) / 256)

__global__ __launch_bounds__(256) void prep_kernel(
    const float* __restrict__ fc_w, const float* __restrict__ attn_l,
    ushort* __restrict__ Bt, float* __restrict__ wl,
    const int* __restrict__ dst, int* __restrict__ row_ptr) {
  __shared__ float tile[32][33];
  const int b = blockIdx.x;
  const int t = threadIdx.x;

  if (b < 64) {
    // --- Bt[n][k] = bf16(fc_w[k][n]), 32x32 tile
    const int bx = (b & 7) * 32;   // n block
    const int by = (b >> 3) * 32;  // k block
    const int tx = t & 31;
    const int ty = t >> 5;  // 0..7
#pragma unroll
    for (int i = 0; i < 32; i += 8)
      tile[ty + i][tx] = fc_w[(size_t)(by + ty + i) * HF + bx + tx];
    __syncthreads();
#pragma unroll
    for (int i = 0; i < 32; i += 8)
      Bt[(size_t)(bx + ty + i) * IN_F + by + tx] = f2bf(tile[tx][ty + i]);
  } else if (b == 64) {
    // --- wl[k,h] = sum_f fc_w[k, h*32+f] * attn_l[h,f]
#pragma unroll
    for (int ii = 0; ii < 8; ++ii) {
      const int idx = ii * 256 + t;  // 0..2047
      const int k = idx >> 3;
      const int h = idx & 7;
      const float* fp = &fc_w[(size_t)k * HF + h * OUT_F];
      const float* ap = &attn_l[h * OUT_F];
      float acc = 0.f;
#pragma unroll
      for (int f = 0; f < OUT_F; f += 4) {
        float4 a = *(const float4*)&fp[f];
        float4 bb = *(const float4*)&ap[f];
        acc += a.x * bb.x + a.y * bb.y + a.z * bb.z + a.w * bb.w;
      }
      wl[idx] = acc;
    }
  } else {
    // --- row_ptr
    const int i = (b - 65) * 256 + t;
    if (i <= N_NODES) {
      int lo = 0, hi = N_EDGES;
      while (lo < hi) {
        int mid = (lo + hi) >> 1;
        if (dst[mid] < i) lo = mid + 1; else hi = mid;
      }
      row_ptr[i] = lo;
    }
  }
}

// ---------------------------------------------------------------------------
// Kernel 1: bf16 MFMA GEMM  Cb[M,256](bf16) = A[M,256](f32) @ B[256,256]
// BM=64 x BN=256 tile, BK=32, 256 threads = 4 waves. Wave w owns cols w*64.
// ---------------------------------------------------------------------------
#define BM 64
#define BN 256
#define BK 32
#define LDA 40   // padded LDS row stride (bf16 elems): 80 B, 16B-aligned

__global__ __launch_bounds__(256) void gemm_mfma(
    const float* __restrict__ A, const ushort* __restrict__ Bt,
    ushort* __restrict__ Cb, int M) {
  __shared__ __align__(16) ushort As[BM * LDA];   // [m][k]  5 KB
  __shared__ __align__(16) ushort Bs[BN * LDA];   // [n][k] 20 KB

  const int t = threadIdx.x;
  const int wave = t >> 6;
  const int lane = t & 63;
  const int m0 = blockIdx.x * BM;

  const int ar = t >> 2;
  const int ak = (t & 3) * 8;
  const int br = t >> 2;
  const int bk = (t & 3) * 8;

  const int q = lane >> 4;
  const int l16 = lane & 15;
  const int wn = wave * 64;

  f32x4 acc[4][4] = {};

  for (int k0 = 0; k0 < IN_F; k0 += BK) {
    {
      float4 v0 = make_float4(0.f, 0.f, 0.f, 0.f);
      float4 v1 = make_float4(0.f, 0.f, 0.f, 0.f);
      if (m0 + ar < M) {
        const float* ap = &A[(size_t)(m0 + ar) * IN_F + k0 + ak];
        v0 = *(const float4*)ap;
        v1 = *(const float4*)(ap + 4);
      }
      union { ushort s[8]; uint4 v; } u;
      u.s[0] = f2bf(v0.x); u.s[1] = f2bf(v0.y);
      u.s[2] = f2bf(v0.z); u.s[3] = f2bf(v0.w);
      u.s[4] = f2bf(v1.x); u.s[5] = f2bf(v1.y);
      u.s[6] = f2bf(v1.z); u.s[7] = f2bf(v1.w);
      *(uint4*)&As[ar * LDA + ak] = u.v;
    }
#pragma unroll
    for (int i = 0; i < 4; ++i) {
      const int n = br + i * 64;
      *(uint4*)&Bs[n * LDA + bk] =
          *(const uint4*)&Bt[(size_t)n * IN_F + k0 + bk];
    }
    __syncthreads();

    bf16x8 aF[4], bF[4];
#pragma unroll
    for (int i = 0; i < 4; ++i)
      aF[i] = *(const bf16x8*)&As[(i * 16 + l16) * LDA + q * 8];
#pragma unroll
    for (int jj = 0; jj < 4; ++jj)
      bF[jj] = *(const bf16x8*)&Bs[(wn + jj * 16 + l16) * LDA + q * 8];
#pragma unroll
    for (int i = 0; i < 4; ++i)
#pragma unroll
      for (int jj = 0; jj < 4; ++jj)
        acc[i][jj] = __builtin_amdgcn_mfma_f32_16x16x32_bf16(
            aF[i], bF[jj], acc[i][jj], 0, 0, 0);
    __syncthreads();
  }

#pragma unroll
  for (int i = 0; i < 4; ++i) {
#pragma unroll
    for (int r = 0; r < 4; ++r) {
      const int row = m0 + 16 * i + q * 4 + r;
      if (row < M) {
#pragma unroll
        for (int jj = 0; jj < 4; ++jj) {
          const int col = wn + 16 * jj + l16;
          Cb[(size_t)row * HF + col] = f2bf(acc[i][jj][r]);
        }
      }
    }
  }
}

// ---------------------------------------------------------------------------
// Kernel 3: el[n,h] = sum_k feat[n,k] * wl[k,h]  (round-1 verified version)
// ---------------------------------------------------------------------------
__global__ __launch_bounds__(256) void el_kernel(
    const float* __restrict__ feat, const float* __restrict__ wl,
    float* __restrict__ el, int NH) {
  __shared__ float wls[IN_F * HEADS];  // 8 KB
  const int t = threadIdx.x;
#pragma unroll
  for (int i = 0; i < (IN_F * HEADS) / 256; ++i)
    wls[i * 256 + t] = wl[i * 256 + t];
  __syncthreads();

  const int idx = blockIdx.x * 256 + t;
  if (idx >= NH) return;
  const int n = idx >> 3;
  const int h = idx & 7;
  const float* fp = &feat[(size_t)n * IN_F];
  float acc = 0.f;
#pragma unroll 8
  for (int k0 = 0; k0 < IN_F; k0 += 4) {
    float4 v = *(const float4*)&fp[k0];
    acc += v.x * wls[(k0 + 0) * 8 + h] + v.y * wls[(k0 + 1) * 8 + h] +
           v.z * wls[(k0 + 2) * 8 + h] + v.w * wls[(k0 + 3) * 8 + h];
  }
  el[idx] = acc;
}

// ---------------------------------------------------------------------------
// Kernel 5: per-destination softmax + weighted aggregation.
// WAVE-PER-NODE, zero barriers/LDS. Round 8 change: gather-row broadcast
// uses __builtin_amdgcn_readlane (compile-time lane index) instead of
// __shfl/ds_bpermute. The row index lands in an SGPR, the row base becomes
// SALU math, and the gather is a saddr global_load_dwordx2 with a constant
// per-lane voffset — removing 8 ds_bpermutes + per-lane 64-bit address
// VALU per pass. Loads, values, and accumulation order are unchanged.
// ---------------------------------------------------------------------------
__global__ __launch_bounds__(256) void aggregate_kernel(
    const ushort* __restrict__ featb, const float* __restrict__ el,
    const int* __restrict__ src, const int* __restrict__ row_ptr,
    float* __restrict__ out) {
  const int t = threadIdx.x;
  const int wave = t >> 6;
  const int lane = t & 63;
  const int v = blockIdx.x * 4 + wave;   // N = 50000 = 12500*4 exactly

  const int beg = row_ptr[v];
  const int deg = row_ptr[v + 1] - beg;

  const int j = lane >> 3;   // edge slot (== gather head)
  const int h8 = lane & 7;   // head for score lanes

  float4 acc = make_float4(0.f, 0.f, 0.f, 0.f);

  if (deg == 0) {  // segment_sum over empty segment = 0
    *(float4*)&out[(size_t)v * HF + lane * 4] = acc;
    return;
  }

  const ushort* fb_lane = featb + lane * 4;  // per-lane feature offset
  float ssum = 0.f;

  if (deg <= 64) {
    const int npass = (deg + 7) >> 3;  // wave-uniform, 1..8

    // ---- 1. src indices (all passes)
    int sidx[8];
#pragma unroll
    for (int p = 0; p < 8; ++p) {
      sidx[p] = 0;
      if (p < npass) {
        const int e = p * 8 + j;
        if (e < deg) sidx[p] = src[beg + e];
      }
    }

    // ---- 2. issue first 16 gather loads NOW (independent of scores)
    uint2 u[16];
#pragma unroll
    for (int ee = 0; ee < 8; ++ee) {
      const int sb = __builtin_amdgcn_readlane(sidx[0], ee * 8);
      u[ee] = *(const uint2*)&fb_lane[(size_t)sb * HF];
    }
#pragma unroll
    for (int ee = 0; ee < 8; ++ee) {
      const int sb = __builtin_amdgcn_readlane(sidx[1], ee * 8);
      u[8 + ee] = *(const uint2*)&fb_lane[(size_t)sb * HF];
    }

    // ---- 3. score loads + max + coeffs (hidden under the gathers above)
    float vel[8];
#pragma unroll
    for (int p = 0; p < 8; ++p) {
      vel[p] = -1e30f;
      if (p < npass && p * 8 + j < deg)
        vel[p] = el[(size_t)sidx[p] * HEADS + h8];
    }
    float mx = -1e30f;
#pragma unroll
    for (int p = 0; p < 8; ++p) mx = fmaxf(mx, vel[p]);
    mx = fmaxf(mx, __shfl_xor(mx, 8));
    mx = fmaxf(mx, __shfl_xor(mx, 16));
    mx = fmaxf(mx, __shfl_xor(mx, 32));

    float cf[8];
#pragma unroll
    for (int p = 0; p < 8; ++p) {
      cf[p] = 0.f;
      if (p < npass && p * 8 + j < deg) {
        const float z = vel[p] - mx;
        const float w = (z >= 0.f) ? z : SLOPE * z;
        cf[p] = __expf(w);
      }
    }
    // ssum association identical to rounds 6/7 (per-pair sums)
#pragma unroll
    for (int p2 = 0; p2 < 8; p2 += 2)
      if (p2 < npass) ssum += cf[p2] + cf[p2 + 1];

    // ---- 4. consume passes 0,1 (already loaded)
#pragma unroll
    for (int ee = 0; ee < 8; ++ee) {
      const float a = __shfl(cf[0], ee * 8 + j);
      acc.x = fmaf(a, bf2f_lo(u[ee].x), acc.x);
      acc.y = fmaf(a, bf2f_hi(u[ee].x), acc.y);
      acc.z = fmaf(a, bf2f_lo(u[ee].y), acc.z);
      acc.w = fmaf(a, bf2f_hi(u[ee].y), acc.w);
    }
#pragma unroll
    for (int ee = 0; ee < 8; ++ee) {
      const float a = __shfl(cf[1], ee * 8 + j);  // 0 for pads: exact no-op
      acc.x = fmaf(a, bf2f_lo(u[8 + ee].x), acc.x);
      acc.y = fmaf(a, bf2f_hi(u[8 + ee].x), acc.y);
      acc.z = fmaf(a, bf2f_lo(u[8 + ee].y), acc.z);
      acc.w = fmaf(a, bf2f_hi(u[8 + ee].y), acc.w);
    }

    // ---- 5. remaining passes, 16-deep pass pairs
#pragma unroll
    for (int p2 = 2; p2 < 8; p2 += 2) {
      if (p2 < npass) {
#pragma unroll
        for (int ee = 0; ee < 8; ++ee) {
          const int sb = __builtin_amdgcn_readlane(sidx[p2], ee * 8);
          u[ee] = *(const uint2*)&fb_lane[(size_t)sb * HF];
        }
#pragma unroll
        for (int ee = 0; ee < 8; ++ee) {
          const int sb = __builtin_amdgcn_readlane(sidx[p2 + 1], ee * 8);
          u[8 + ee] = *(const uint2*)&fb_lane[(size_t)sb * HF];
        }
#pragma unroll
        for (int ee = 0; ee < 8; ++ee) {
          const float a = __shfl(cf[p2], ee * 8 + j);
          acc.x = fmaf(a, bf2f_lo(u[ee].x), acc.x);
          acc.y = fmaf(a, bf2f_hi(u[ee].x), acc.y);
          acc.z = fmaf(a, bf2f_lo(u[ee].y), acc.z);
          acc.w = fmaf(a, bf2f_hi(u[ee].y), acc.w);
        }
#pragma unroll
        for (int ee = 0; ee < 8; ++ee) {
          const float a = __shfl(cf[p2 + 1], ee * 8 + j);
          acc.x = fmaf(a, bf2f_lo(u[8 + ee].x), acc.x);
          acc.y = fmaf(a, bf2f_hi(u[8 + ee].x), acc.y);
          acc.z = fmaf(a, bf2f_lo(u[8 + ee].y), acc.z);
          acc.w = fmaf(a, bf2f_hi(u[8 + ee].y), acc.w);
        }
      }
    }
  } else {
    // ---- rare fallback: streamed passes of 8 edges
    float mx = -1e30f;
    for (int e = j; e < deg; e += 8)
      mx = fmaxf(mx, el[(size_t)src[beg + e] * HEADS + h8]);
    mx = fmaxf(mx, __shfl_xor(mx, 8));
    mx = fmaxf(mx, __shfl_xor(mx, 16));
    mx = fmaxf(mx, __shfl_xor(mx, 32));

    for (int p0 = 0; p0 < deg; p0 += 8) {
      float cf = 0.f;
      int sx = 0;
      if (p0 + j < deg) {
        sx = src[beg + p0 + j];
        const float z = el[(size_t)sx * HEADS + h8] - mx;
        const float w = (z >= 0.f) ? z : SLOPE * z;
        cf = __expf(w);
      }
      ssum += cf;
      const int emax = min(8, deg - p0);  // wave-uniform
      for (int ee = 0; ee < emax; ++ee) {
        const float a = __shfl(cf, ee * 8 + j);
        const int sb = __builtin_amdgcn_readlane(sx, ee * 8);
        const uint2 u2 = *(const uint2*)&fb_lane[(size_t)sb * HF];
        acc.x = fmaf(a, bf2f_lo(u2.x), acc.x);
        acc.y = fmaf(a, bf2f_hi(u2.x), acc.y);
        acc.z = fmaf(a, bf2f_lo(u2.y), acc.z);
        acc.w = fmaf(a, bf2f_hi(u2.y), acc.w);
      }
    }
  }

  // ---- coeff-sum reduce over edge slots, broadcast head j's sum, normalize
  ssum += __shfl_xor(ssum, 8);
  ssum += __shfl_xor(ssum, 16);
  ssum += __shfl_xor(ssum, 32);
  const float inv = 1.0f / __shfl(ssum, j);  // lane j holds head-j sum (h8==j)
  acc.x *= inv; acc.y *= inv; acc.z *= inv; acc.w *= inv;
  *(float4*)&out[(size_t)v * HF + lane * 4] = acc;
}

// ---------------------------------------------------------------------------
extern "C" void kernel_launch(void* const* d_in, const int* in_sizes, int n_in,
                              void* d_out, int out_size, void* d_ws,
                              size_t ws_size, hipStream_t stream) {
  const float* feat = (const float*)d_in[0];
  const float* fc_w = (const float*)d_in[1];
  const float* attn_l = (const float*)d_in[2];
  // d_in[3] = attn_r: unused — cancels exactly in the edge softmax.
  const int* src = (const int*)d_in[4];
  const int* dst = (const int*)d_in[5];
  float* out = (float*)d_out;

  const int N = N_NODES;

  // workspace layout (16B-aligned sections)
  ushort* featb = (ushort*)d_ws;                       // N*256 bf16 (25.6 MB)
  float* el = (float*)(featb + (size_t)N * HF);        // N*8 f32
  float* wl = el + (size_t)N * HEADS;                  // 256*8 f32
  ushort* Bt = (ushort*)(wl + IN_F * HEADS);           // 256*256 bf16 (128 KB)
  int* row_ptr = (int*)(Bt + (size_t)IN_F * HF);       // N+1 ints

  prep_kernel<<<65 + ROWPTR_BLOCKS, 256, 0, stream>>>(fc_w, attn_l, Bt, wl,
                                                      dst, row_ptr);

  gemm_mfma<<<(N + BM - 1) / BM, 256, 0, stream>>>(feat, Bt, featb, N);

  el_kernel<<<(N * HEADS + 255) / 256, 256, 0, stream>>>(feat, wl, el,
                                                         N * HEADS);

  aggregate_kernel<<<N / 4, 256, 0, stream>>>(featb, el, src, row_ptr, out);
}